// Round 2
// baseline (1556.073 us; speedup 1.0000x reference)
//
#include <hip/hip_runtime.h>
#include <hip/hip_bf16.h>

// HetGNN fused kernel, round 2: f32 input/output storage (round-1 NaN was
// f32 buffers misread as bf16). Weights staged f32->bf16 into LDS (96 KB);
// all arithmetic f32. One wave per graph-slot, 4 graphs/wave, 4 waves/block.

#define NBLK    1024     // 4 waves/block * 4 graphs/wave * 1024 = 16384
#define GPW     4        // graphs per wave
#define RS      68       // row stride in floats (64 + 4 pad, keeps 16B align)

typedef unsigned short u16;
typedef unsigned int   u32;

struct Params {
  const float *ap, *ef;
  const float *wpa, *bpa, *wpe, *bpe;
  const float *w51, *b51, *w52, *b52, *w53, *b53;
  const float *w61, *b61, *w62, *b62, *w63, *b63;
  const float *w71, *b71, *w72, *b72, *w73, *b73;
  const float *wpost, *bpost;
  float *out;
  int gtot;
};

__device__ __forceinline__ float bf2f(u16 v) {
  return __uint_as_float(((u32)v) << 16);
}
__device__ __forceinline__ u16 f2bf(float f) {
  u32 x = __float_as_uint(f);
  u32 r = (x + 0x7fff + ((x >> 16) & 1)) >> 16;  // RNE
  return (u16)r;
}

// acc[r] += sum_{din=0..63} X[(r/RDIV)*RS+din] * bf2f(W[din*64+lane])
// X reads are wave-uniform broadcasts (float4); W reads are per-lane columns.
template<int NR, int RDIV>
__device__ __forceinline__ void mm_acc(float* acc, const float* X,
                                       const u16* W, int lane) {
  for (int d4 = 0; d4 < 64; d4 += 4) {
    const float w0 = bf2f(W[(d4 + 0) * 64 + lane]);
    const float w1 = bf2f(W[(d4 + 1) * 64 + lane]);
    const float w2 = bf2f(W[(d4 + 2) * 64 + lane]);
    const float w3 = bf2f(W[(d4 + 3) * 64 + lane]);
#pragma unroll
    for (int r = 0; r < NR; ++r) {
      const float4 x = *reinterpret_cast<const float4*>(X + (r / RDIV) * RS + d4);
      acc[r] = fmaf(x.x, w0, fmaf(x.y, w1, fmaf(x.z, w2, fmaf(x.w, w3, acc[r]))));
    }
  }
}

__global__ __launch_bounds__(256, 1) void hetgnn_kernel(Params p) {
  // LDS: 98304 (weights bf16) + 2304 (bias f32) + 2048 (pre/post f32)
  //      + 39168 (4 waves x 36 rows x 68 f32) = ~141.8 KB (<160 KB)
  __shared__ __align__(16) u16   sW[49152];
  __shared__ __align__(16) float sBias[576];
  __shared__ __align__(16) float sPre[512];
  __shared__ __align__(16) float sRow[4][36 * RS];

  const int tid = threadIdx.x;

  // ---------------- stage weights/biases into LDS (f32 -> bf16) ----------------
  {
    const float* srcs[9] = {p.w51, p.w52, p.w53, p.w61, p.w62, p.w63, p.w71, p.w72, p.w73};
    const int  offs[9] = {0, 8192, 12288, 16384, 24576, 28672, 32768, 40960, 45056};
    const int  szs[9]  = {8192, 4096, 4096, 8192, 4096, 4096, 8192, 4096, 4096};
#pragma unroll
    for (int m = 0; m < 9; ++m) {
      const float4* s = reinterpret_cast<const float4*>(srcs[m]);
      ushort4* d = reinterpret_cast<ushort4*>(sW + offs[m]);
      const int n4 = szs[m] >> 2;
      for (int i = tid; i < n4; i += 256) {
        const float4 v = s[i];
        ushort4 o;
        o.x = f2bf(v.x); o.y = f2bf(v.y); o.z = f2bf(v.z); o.w = f2bf(v.w);
        d[i] = o;
      }
    }
    if (tid < 64) {
      sBias[tid]        = p.b51[tid];
      sBias[64 + tid]   = p.b52[tid];
      sBias[128 + tid]  = p.b53[tid];
      sBias[192 + tid]  = p.b61[tid];
      sBias[256 + tid]  = p.b62[tid];
      sBias[320 + tid]  = p.b63[tid];
      sBias[384 + tid]  = p.b71[tid];
      sBias[448 + tid]  = p.b72[tid];
      sBias[512 + tid]  = p.b73[tid];
      sPre[tid]         = p.wpa[tid];   // w_pre_ap [1][64]
      sPre[64 + tid]    = p.bpa[tid];
      sPre[256 + tid]   = p.bpe[tid];
    }
    if (tid < 128) {
      sPre[128 + tid] = p.wpe[tid];     // w_pre_edge [2][64]
      sPre[320 + tid] = p.wpost[tid];   // w_post [64][2]
    }
    if (tid < 2) sPre[448 + tid] = p.bpost[tid];
  }
  __syncthreads();

  const int lane = tid & 63;
  const int wave = tid >> 6;
  float* RB = sRow[wave];
  float* Ab = RB;            // 4 rows: a[b]
  float* Eb = RB + 4 * RS;   // 8 rows: e[(b,k)]
  float* T1 = RB + 12 * RS;  // 8 rows temp
  float* T2 = RB + 20 * RS;  // 8 rows temp
  float* AG = RB + 28 * RS;  // 8 rows: agg

  const u16* W51t = sW;              const u16* W51b = sW + 4096;
  const u16* W52  = sW + 8192;       const u16* W53  = sW + 12288;
  const u16* W61t = sW + 16384;      const u16* W61b = sW + 20480;
  const u16* W62  = sW + 24576;      const u16* W63  = sW + 28672;
  const u16* W71t = sW + 32768;      const u16* W71b = sW + 36864;
  const u16* W72  = sW + 40960;      const u16* W73  = sW + 45056;

  const int wslot = blockIdx.x * 4 + wave;

  for (int gi = 0; gi < GPW; ++gi) {
    const int g = wslot * GPW + gi;
    if (g >= p.gtot) break;

    // ---------------- pre-layer ----------------
    {
      const float wpav = sPre[lane], bpav = sPre[64 + lane];
#pragma unroll
      for (int b = 0; b < 4; ++b) {
        const float apv = p.ap[g * 4 + b];
        Ab[b * RS + lane] = fmaxf(fmaf(apv, wpav, bpav), 0.f);
      }
      const float we0 = sPre[128 + lane], we1 = sPre[192 + lane];
      const float bpev = sPre[256 + lane];
#pragma unroll
      for (int r = 0; r < 8; ++r) {
        const float f0 = p.ef[g * 16 + r * 2 + 0];
        const float f1 = p.ef[g * 16 + r * 2 + 1];
        Eb[r * RS + lane] = fmaxf(fmaf(f0, we0, fmaf(f1, we1, bpev)), 0.f);
      }
    }

    // ---------------- 2 shared-weight update iterations ----------------
#pragma unroll 1
    for (int it = 0; it < 2; ++it) {
      float m1r[8];  // M1 rows (lane = dout), kept in regs
      // ---- mlp5: x = cat(a[b], e[b,j]) ----
      {
        float acc[8];
#pragma unroll
        for (int r = 0; r < 8; ++r) acc[r] = sBias[lane];
        mm_acc<8, 2>(acc, Ab, W51t, lane);   // row r uses a[r>>1]
        mm_acc<8, 1>(acc, Eb, W51b, lane);
#pragma unroll
        for (int r = 0; r < 8; ++r) T1[r * RS + lane] = fmaxf(acc[r], 0.f);
        float acc2[8];
#pragma unroll
        for (int r = 0; r < 8; ++r) acc2[r] = sBias[64 + lane];
        mm_acc<8, 1>(acc2, T1, W52, lane);
#pragma unroll
        for (int r = 0; r < 8; ++r) T2[r * RS + lane] = fmaxf(acc2[r], 0.f);
        float acc3[8];
#pragma unroll
        for (int r = 0; r < 8; ++r) acc3[r] = sBias[128 + lane];
        mm_acc<8, 1>(acc3, T2, W53, lane);
#pragma unroll
        for (int r = 0; r < 8; ++r) m1r[r] = fmaxf(acc3[r], 0.f);
      }

      // ---- mlp6: split first linear, bp-batched, running masked max ----
      float m2r[8];
      {
        float aP[4] = {0.f, 0.f, 0.f, 0.f};
        mm_acc<4, 1>(aP, Ab, W61t, lane);        // a @ w6_1[:D]
        float eP[8] = {0.f, 0.f, 0.f, 0.f, 0.f, 0.f, 0.f, 0.f};
        mm_acc<8, 1>(eP, Eb, W61b, lane);        // e @ w6_1[D:]
        const float b61v = sBias[192 + lane];
#pragma unroll
        for (int r = 0; r < 8; ++r) m2r[r] = -1e30f;
#pragma unroll 1
        for (int bp = 0; bp < 4; ++bp) {
#pragma unroll
          for (int rr = 0; rr < 8; ++rr)  // rr = b*2+k; h[b,bp,k]
            T1[rr * RS + lane] = fmaxf(aP[rr >> 1] + eP[bp * 2 + (rr & 1)] + b61v, 0.f);
          float a2[8];
#pragma unroll
          for (int rr = 0; rr < 8; ++rr) a2[rr] = sBias[256 + lane];
          mm_acc<8, 1>(a2, T1, W62, lane);
#pragma unroll
          for (int rr = 0; rr < 8; ++rr) T2[rr * RS + lane] = fmaxf(a2[rr], 0.f);
          float a3[8];
#pragma unroll
          for (int rr = 0; rr < 8; ++rr) a3[rr] = sBias[320 + lane];
          mm_acc<8, 1>(a3, T2, W63, lane);
#pragma unroll
          for (int rr = 0; rr < 8; ++rr) {
            const float v = fmaxf(a3[rr], 0.f);
            if ((rr >> 1) != bp) m2r[rr] = fmaxf(m2r[rr], v);  // exclude bp==b
          }
        }
      }

      // ---- agg + mlp7 (writes new e into Eb) ----
      {
        // m1max[b,k] = M1[b,1-k]  (K==2: self-exclusion leaves one edge)
#pragma unroll
        for (int r = 0; r < 8; ++r) AG[r * RS + lane] = fmaxf(m1r[r ^ 1], m2r[r]);
        float acc[8];
#pragma unroll
        for (int r = 0; r < 8; ++r) acc[r] = sBias[384 + lane];
        mm_acc<8, 1>(acc, AG, W71t, lane);
        mm_acc<8, 1>(acc, Eb, W71b, lane);
#pragma unroll
        for (int r = 0; r < 8; ++r) T1[r * RS + lane] = fmaxf(acc[r], 0.f);
        float acc2[8];
#pragma unroll
        for (int r = 0; r < 8; ++r) acc2[r] = sBias[448 + lane];
        mm_acc<8, 1>(acc2, T1, W72, lane);
#pragma unroll
        for (int r = 0; r < 8; ++r) T2[r * RS + lane] = fmaxf(acc2[r], 0.f);
        float acc3[8];
#pragma unroll
        for (int r = 0; r < 8; ++r) acc3[r] = sBias[512 + lane];
        mm_acc<8, 1>(acc3, T2, W73, lane);
#pragma unroll
        for (int r = 0; r < 8; ++r) Eb[r * RS + lane] = fmaxf(acc3[r], 0.f);
      }
    }

    // ---------------- post linear + per-(g,b) row normalization ----------------
    {
      const float wr = sPre[320 + lane * 2 + 0];
      const float wi = sPre[320 + lane * 2 + 1];
      const float bpr = sPre[448], bpi = sPre[449];
      float myval = 0.f, n2 = 0.f;
#pragma unroll
      for (int r = 0; r < 8; ++r) {  // r = b*2+k
        const float ev = Eb[r * RS + lane];
        float pr = ev * wr, pi = ev * wi;
#pragma unroll
        for (int off = 32; off > 0; off >>= 1) {
          pr += __shfl_xor(pr, off, 64);
          pi += __shfl_xor(pi, off, 64);
        }
        pr += bpr; pi += bpi;
        if ((lane >> 1) == r) myval = (lane & 1) ? pi : pr;   // out[g,b,k,c]
        if ((lane >> 2) == (r >> 1)) n2 += pr * pr + pi * pi; // sum over k for my b
      }
      if (lane < 16) p.out[g * 16 + lane] = myval / sqrtf(n2);
    }
  }
}

extern "C" void kernel_launch(void* const* d_in, const int* in_sizes, int n_in,
                              void* d_out, int out_size, void* d_ws, size_t ws_size,
                              hipStream_t stream) {
  Params p;
  p.ap    = (const float*)d_in[0];
  p.ef    = (const float*)d_in[1];
  p.wpa   = (const float*)d_in[2];  p.bpa   = (const float*)d_in[3];
  p.wpe   = (const float*)d_in[4];  p.bpe   = (const float*)d_in[5];
  p.w51   = (const float*)d_in[6];  p.b51   = (const float*)d_in[7];
  p.w52   = (const float*)d_in[8];  p.b52   = (const float*)d_in[9];
  p.w53   = (const float*)d_in[10]; p.b53   = (const float*)d_in[11];
  p.w61   = (const float*)d_in[12]; p.b61   = (const float*)d_in[13];
  p.w62   = (const float*)d_in[14]; p.b62   = (const float*)d_in[15];
  p.w63   = (const float*)d_in[16]; p.b63   = (const float*)d_in[17];
  p.w71   = (const float*)d_in[18]; p.b71   = (const float*)d_in[19];
  p.w72   = (const float*)d_in[20]; p.b72   = (const float*)d_in[21];
  p.w73   = (const float*)d_in[22]; p.b73   = (const float*)d_in[23];
  p.wpost = (const float*)d_in[24]; p.bpost = (const float*)d_in[25];
  p.out   = (float*)d_out;
  p.gtot  = in_sizes[0] / 4;  // G from ap_feat [G,B,1]

  hipLaunchKernelGGL(hetgnn_kernel, dim3(NBLK), dim3(256), 0, stream, p);
}

// Round 3
// 388.850 us; speedup vs baseline: 4.0017x; 4.0017x over previous
//
#include <hip/hip_runtime.h>

// HetGNN fused kernel, round 3: MFMA restructure.
// - mfma_f32_16x16x32_bf16, M=16 rows per pass, 2 graphs per wave.
// - Weights pre-swizzled into d_ws in B-fragment order by a setup kernel;
//   main kernel reads B-frags as global_load_dwordx4 (VMEM pipe, L1/L2-hot).
// - Activations staged in per-wave LDS buffers in A-fragment-swizzled bf16:
//   A-frag read = one aligned conflict-free ds_read_b128 (lane's own 16B slot).
//   C-layout -> A-layout transition = 16 scattered ds_write_b16 per layer.
// - aP/eP (mlp6 first-linear partials) staged f32 (protects the h=aP+eP+b sum).
// - m1/m2/agg kept in C-layout registers; K=2 self-exclusion = reg swap.
// - No block-shared LDS, no __syncthreads; 64 KB LDS -> 2 blocks/CU.

typedef unsigned short u16;
typedef unsigned int   u32;
typedef __attribute__((ext_vector_type(8))) short short8_t;
typedef __attribute__((ext_vector_type(4))) float floatx4;

// u16 offsets of each matrix's fragment block inside d_ws.
// K=128 mats have 16 frags (t*4+h), K=64 mats 8 frags (t*2+h); 512 u16 each.
#define OFF_W51 0
#define OFF_W61 8192
#define OFF_W71 16384
#define OFF_W52 24576
#define OFF_W53 28672
#define OFF_W62 32768
#define OFF_W63 36864
#define OFF_W72 40960
#define OFF_W73 45056
#define WS_U16  49152   // 96 KB total

struct Params {
  const float *ap, *ef;
  const float *wpa, *bpa, *wpe, *bpe;
  const float *w51, *b51, *w52, *b52, *w53, *b53;
  const float *w61, *b61, *w62, *b62, *w63, *b63;
  const float *w71, *b71, *w72, *b72, *w73, *b73;
  const float *wpost, *bpost;
  float *out;
  u16 *ws;
  int gtot;
};

__device__ __forceinline__ u16 f2bf(float f) {
  u32 x = __float_as_uint(f);
  return (u16)((x + 0x7fff + ((x >> 16) & 1)) >> 16);  // RNE
}
__device__ __forceinline__ u32 pk2(float a, float b) {
  return (u32)f2bf(a) | ((u32)f2bf(b) << 16);
}

// ---------------- setup: swizzle all 9 weight mats into B-frag order ----------------
// frag fi, lane l, j: value = W[32h + (l>>4)*8 + j][16t + (l&15)]  (W row-major [K][64])
__global__ void swizzle_weights(Params p) {
  const float* mats[9] = {p.w51, p.w61, p.w71, p.w52, p.w53, p.w62, p.w63, p.w72, p.w73};
  const int fi = blockIdx.x;   // 0..95
  const int l  = threadIdx.x;  // 0..63
  const float* W;
  int t, h;
  if (fi < 48) { W = mats[fi >> 4]; const int loc = fi & 15; t = loc >> 2; h = loc & 3; }
  else { const int j = fi - 48; W = mats[3 + (j >> 3)]; const int loc = j & 7; t = loc >> 1; h = loc & 1; }
  const int n  = 16 * t + (l & 15);
  const int k0 = 32 * h + (l >> 4) * 8;
  u16* dst = p.ws + fi * 512 + l * 8;
#pragma unroll
  for (int j = 0; j < 8; ++j) dst[j] = f2bf(W[(k0 + j) * 64 + n]);
}

// ---------------- main kernel helpers ----------------
__device__ __forceinline__ floatx4 mfma16(short8_t a, short8_t b, floatx4 c) {
  return __builtin_amdgcn_mfma_f32_16x16x32_bf16(a, b, c, 0, 0, 0);
}

// K=64 layer: A from one LDS buffer (2 frags), B frags at B + (t*TSTRIDE+h)*512.
template<int TSTRIDE>
__device__ __forceinline__ void layerK64(floatx4* acc, const u16* A, const u16* B, int l) {
  const short8_t a0 = *(const short8_t*)(A + l * 8);
  const short8_t a1 = *(const short8_t*)(A + 512 + l * 8);
#pragma unroll
  for (int t = 0; t < 4; ++t) {
    const short8_t b0 = *(const short8_t*)(B + (t * TSTRIDE + 0) * 512 + l * 8);
    const short8_t b1 = *(const short8_t*)(B + (t * TSTRIDE + 1) * 512 + l * 8);
    acc[t] = mfma16(a0, b0, acc[t]);
    acc[t] = mfma16(a1, b1, acc[t]);
  }
}

// K=128 layer: A = cat(A0 rows, A1 rows) over K; B has 16 frags (t*4+h).
__device__ __forceinline__ void layerK128(floatx4* acc, const u16* A0, const u16* A1,
                                          const u16* B, int l) {
  short8_t a[4];
  a[0] = *(const short8_t*)(A0 + l * 8);
  a[1] = *(const short8_t*)(A0 + 512 + l * 8);
  a[2] = *(const short8_t*)(A1 + l * 8);
  a[3] = *(const short8_t*)(A1 + 512 + l * 8);
#pragma unroll
  for (int t = 0; t < 4; ++t)
#pragma unroll
    for (int h = 0; h < 4; ++h)
      acc[t] = mfma16(a[h], *(const short8_t*)(B + (t * 4 + h) * 512 + l * 8), acc[t]);
}

// C-layout regs -> A-frag-swizzled bf16 LDS (with relu). Element (m=4q+r, k=16t+n).
__device__ __forceinline__ void scatter_relu_bf16(u16* dst, const floatx4* acc, int q, int n) {
#pragma unroll
  for (int t = 0; t < 4; ++t) {
    const int kk = (t & 1) * 2 + (n >> 3);          // (k&31)>>3
    u16* base = dst + (t >> 1) * 512 + (n & 7);
#pragma unroll
    for (int r = 0; r < 4; ++r)
      base[(4 * q + r + 16 * kk) * 8] = f2bf(fmaxf(acc[t][r], 0.f));
  }
}

// Same scatter but raw f32 (no relu) into an f32 swizzled buffer (aP/eP).
__device__ __forceinline__ void scatter_f32(float* dst, const floatx4* acc, int q, int n) {
#pragma unroll
  for (int t = 0; t < 4; ++t) {
    const int kk = (t & 1) * 2 + (n >> 3);
    float* base = dst + (t >> 1) * 512 + (n & 7);
#pragma unroll
    for (int r = 0; r < 4; ++r)
      base[(4 * q + r + 16 * kk) * 8] = acc[t][r];
  }
}

__device__ __forceinline__ void init_acc(floatx4* acc, const float* bias) {
#pragma unroll
  for (int t = 0; t < 4; ++t) {
    floatx4 v; v[0] = bias[t]; v[1] = bias[t]; v[2] = bias[t]; v[3] = bias[t];
    acc[t] = v;
  }
}

#define NBLK 512
#define PPW  4   // graph-pairs per wave: 512 blk * 4 waves * 4 = 8192 pairs = 16384 graphs

__global__ __launch_bounds__(256, 2) void hetgnn_mfma(Params p) {
  // Per-wave private LDS. bf16 bufs: Ab16, Eb, T1, T2 (1024 u16 = 2 KB each).
  // f32 bufs: aP, eP (1024 f32 = 4 KB each). Total 16 KB/wave -> 64 KB/block.
  __shared__ __align__(16) u16   sB[4][4096];
  __shared__ __align__(16) float sF[4][2048];

  const int tid  = threadIdx.x;
  const int wave = tid >> 6;
  const int l    = tid & 63;
  const int q    = l >> 4;     // quad
  const int n    = l & 15;     // column within C-tile

  u16* Ab = sB[wave];
  u16* Eb = Ab + 1024;
  u16* T1 = Ab + 2048;
  u16* T2 = Ab + 3072;
  float* aP = sF[wave];
  float* eP = aP + 1024;

  const u16* ws = p.ws;

  // ---- lane-resident constants ----
  float b51c[4], b52c[4], b53c[4], b62c[4], b63c[4], b71c[4], b72c[4], b73c[4];
#pragma unroll
  for (int t = 0; t < 4; ++t) {
    const int f = 16 * t + n;
    b51c[t] = p.b51[f]; b52c[t] = p.b52[f]; b53c[t] = p.b53[f];
    b62c[t] = p.b62[f]; b63c[t] = p.b63[f];
    b71c[t] = p.b71[f]; b72c[t] = p.b72[f]; b73c[t] = p.b73[f];
  }
  float4 b61C[2][2];   // b61[32h + 8q + j]
#pragma unroll
  for (int h = 0; h < 2; ++h) {
    b61C[h][0] = *(const float4*)(p.b61 + 32 * h + 8 * q);
    b61C[h][1] = *(const float4*)(p.b61 + 32 * h + 8 * q + 4);
  }
  float wpR[4], wpI[4];
#pragma unroll
  for (int t = 0; t < 4; ++t) {
    wpR[t] = p.wpost[(16 * t + n) * 2];
    wpI[t] = p.wpost[(16 * t + n) * 2 + 1];
  }
  const float bpR = p.bpost[0], bpI = p.bpost[1];

  const int wslot = blockIdx.x * 4 + wave;

  for (int pi = 0; pi < PPW; ++pi) {
    const int pr_idx = wslot * PPW + pi;
    const int g0 = pr_idx * 2;             // 2 graphs: g0, g0+1
    if (g0 + 1 >= p.gtot + 1) break;       // g0+1 <= gtot-1  <=>  g0+2 <= gtot
    if (g0 + 2 > p.gtot) break;

    // ---------------- pre-layer: fill Ab16 (a rows duplicated) + Eb, swizzled ----------------
    {
      const float apv = p.ap[(g0 + (n >> 3)) * 4 + ((n >> 1) & 3)];
      const float f0  = p.ef[(g0 + (n >> 3)) * 16 + (n & 7) * 2];
      const float f1  = p.ef[(g0 + (n >> 3)) * 16 + (n & 7) * 2 + 1];
#pragma unroll
      for (int h = 0; h < 2; ++h) {
        const int fb = 32 * h + 8 * q;
        const float4 wa0 = *(const float4*)(p.wpa + fb);
        const float4 wa1 = *(const float4*)(p.wpa + fb + 4);
        const float4 ba0 = *(const float4*)(p.bpa + fb);
        const float4 ba1 = *(const float4*)(p.bpa + fb + 4);
        uint4 pa;
        pa.x = pk2(fmaxf(fmaf(apv, wa0.x, ba0.x), 0.f), fmaxf(fmaf(apv, wa0.y, ba0.y), 0.f));
        pa.y = pk2(fmaxf(fmaf(apv, wa0.z, ba0.z), 0.f), fmaxf(fmaf(apv, wa0.w, ba0.w), 0.f));
        pa.z = pk2(fmaxf(fmaf(apv, wa1.x, ba1.x), 0.f), fmaxf(fmaf(apv, wa1.y, ba1.y), 0.f));
        pa.w = pk2(fmaxf(fmaf(apv, wa1.z, ba1.z), 0.f), fmaxf(fmaf(apv, wa1.w, ba1.w), 0.f));
        *(uint4*)(Ab + h * 512 + l * 8) = pa;

        const float4 w00 = *(const float4*)(p.wpe + fb);
        const float4 w01 = *(const float4*)(p.wpe + fb + 4);
        const float4 w10 = *(const float4*)(p.wpe + 64 + fb);
        const float4 w11 = *(const float4*)(p.wpe + 64 + fb + 4);
        const float4 be0 = *(const float4*)(p.bpe + fb);
        const float4 be1 = *(const float4*)(p.bpe + fb + 4);
        uint4 pe;
        pe.x = pk2(fmaxf(fmaf(f0, w00.x, fmaf(f1, w10.x, be0.x)), 0.f),
                   fmaxf(fmaf(f0, w00.y, fmaf(f1, w10.y, be0.y)), 0.f));
        pe.y = pk2(fmaxf(fmaf(f0, w00.z, fmaf(f1, w10.z, be0.z)), 0.f),
                   fmaxf(fmaf(f0, w00.w, fmaf(f1, w10.w, be0.w)), 0.f));
        pe.z = pk2(fmaxf(fmaf(f0, w01.x, fmaf(f1, w11.x, be1.x)), 0.f),
                   fmaxf(fmaf(f0, w01.y, fmaf(f1, w11.y, be1.y)), 0.f));
        pe.w = pk2(fmaxf(fmaf(f0, w01.z, fmaf(f1, w11.z, be1.z)), 0.f),
                   fmaxf(fmaf(f0, w01.w, fmaf(f1, w11.w, be1.w)), 0.f));
        *(uint4*)(Eb + h * 512 + l * 8) = pe;
      }
    }

    // ---------------- 2 shared-weight update iterations ----------------
#pragma unroll 1
    for (int it = 0; it < 2; ++it) {
      // ---- mlp5 -> m1 (C-layout regs) ----
      floatx4 m1[4];
      {
        floatx4 acc[4]; init_acc(acc, b51c);
        layerK128(acc, Ab, Eb, ws + OFF_W51, l);
        scatter_relu_bf16(T1, acc, q, n);
        floatx4 acc2[4]; init_acc(acc2, b52c);
        layerK64<2>(acc2, T1, ws + OFF_W52, l);
        scatter_relu_bf16(T2, acc2, q, n);
        floatx4 acc3[4]; init_acc(acc3, b53c);
        layerK64<2>(acc3, T2, ws + OFF_W53, l);
#pragma unroll
        for (int t = 0; t < 4; ++t)
#pragma unroll
          for (int r = 0; r < 4; ++r) m1[t][r] = fmaxf(acc3[t][r], 0.f);
      }

      // ---- mlp6 -> m2 (masked running max, C-layout regs) ----
      floatx4 m2[4];
#pragma unroll
      for (int t = 0; t < 4; ++t) { m2[t][0] = -1e30f; m2[t][1] = -1e30f; m2[t][2] = -1e30f; m2[t][3] = -1e30f; }
      {
        floatx4 accA[4];
#pragma unroll
        for (int t = 0; t < 4; ++t) { accA[t][0] = 0.f; accA[t][1] = 0.f; accA[t][2] = 0.f; accA[t][3] = 0.f; }
        layerK64<4>(accA, Ab, ws + OFF_W61, l);          // a @ w61[:64]  (frags h=0,1)
        scatter_f32(aP, accA, q, n);
        floatx4 accE[4];
#pragma unroll
        for (int t = 0; t < 4; ++t) { accE[t][0] = 0.f; accE[t][1] = 0.f; accE[t][2] = 0.f; accE[t][3] = 0.f; }
        layerK64<4>(accE, Eb, ws + OFF_W61 + 2 * 512, l); // e @ w61[64:] (frags h=2,3)
        scatter_f32(eP, accE, q, n);

#pragma unroll 1
        for (int bp = 0; bp < 4; ++bp) {
          // h-build: h[m] = relu(aP[m] + eP[re(m)] + b61), written straight into T1 frags
#pragma unroll
          for (int h = 0; h < 2; ++h) {
            const float* apc = aP + (h * 64 + l) * 8;
            const int re = (n & 8) + bp * 2 + (n & 1);
            const float* epc = eP + (h * 64 + re + (l & 48)) * 8;
            const float4 a0 = *(const float4*)apc;
            const float4 a1 = *(const float4*)(apc + 4);
            const float4 e0 = *(const float4*)epc;
            const float4 e1 = *(const float4*)(epc + 4);
            const float4 b0 = b61C[h][0], b1 = b61C[h][1];
            uint4 ph;
            ph.x = pk2(fmaxf(a0.x + e0.x + b0.x, 0.f), fmaxf(a0.y + e0.y + b0.y, 0.f));
            ph.y = pk2(fmaxf(a0.z + e0.z + b0.z, 0.f), fmaxf(a0.w + e0.w + b0.w, 0.f));
            ph.z = pk2(fmaxf(a1.x + e1.x + b1.x, 0.f), fmaxf(a1.y + e1.y + b1.y, 0.f));
            ph.w = pk2(fmaxf(a1.z + e1.z + b1.z, 0.f), fmaxf(a1.w + e1.w + b1.w, 0.f));
            *(uint4*)(T1 + h * 512 + l * 8) = ph;
          }
          floatx4 acc2[4]; init_acc(acc2, b62c);
          layerK64<2>(acc2, T1, ws + OFF_W62, l);
          scatter_relu_bf16(T2, acc2, q, n);
          floatx4 acc3[4]; init_acc(acc3, b63c);
          layerK64<2>(acc3, T2, ws + OFF_W63, l);
#pragma unroll
          for (int t = 0; t < 4; ++t)
#pragma unroll
            for (int r = 0; r < 4; ++r) {
              const float v = fmaxf(acc3[t][r], 0.f);
              const int b = ((4 * q + r) >> 1) & 3;
              if (b != bp) m2[t][r] = fmaxf(m2[t][r], v);
            }
        }
      }

      // ---- agg (regs) + mlp7 ----
      {
        floatx4 ag[4];
#pragma unroll
        for (int t = 0; t < 4; ++t) {
          ag[t][0] = fmaxf(m1[t][1], m2[t][0]);   // m1max[b,k] = M1[b,1-k] -> reg r^1
          ag[t][1] = fmaxf(m1[t][0], m2[t][1]);
          ag[t][2] = fmaxf(m1[t][3], m2[t][2]);
          ag[t][3] = fmaxf(m1[t][2], m2[t][3]);
        }
        scatter_relu_bf16(T1, ag, q, n);          // values >= 0, relu harmless
        floatx4 acc[4]; init_acc(acc, b71c);
        layerK128(acc, T1, Eb, ws + OFF_W71, l);
        scatter_relu_bf16(T2, acc, q, n);
        floatx4 acc2[4]; init_acc(acc2, b72c);
        layerK64<2>(acc2, T2, ws + OFF_W72, l);
        scatter_relu_bf16(T1, acc2, q, n);
        floatx4 acc3[4]; init_acc(acc3, b73c);
        layerK64<2>(acc3, T1, ws + OFF_W73, l);

        if (it == 0) {
          scatter_relu_bf16(Eb, acc3, q, n);      // new e for iteration 2
        } else {
          // ---- post linear + per-(g,b) row L2-normalization, from C-regs ----
          float prr[4] = {0.f, 0.f, 0.f, 0.f}, pii[4] = {0.f, 0.f, 0.f, 0.f};
#pragma unroll
          for (int t = 0; t < 4; ++t)
#pragma unroll
            for (int r = 0; r < 4; ++r) {
              const float e = fmaxf(acc3[t][r], 0.f);
              prr[r] = fmaf(e, wpR[t], prr[r]);
              pii[r] = fmaf(e, wpI[t], pii[r]);
            }
#pragma unroll
          for (int r = 0; r < 4; ++r) {
#pragma unroll
            for (int off = 1; off < 16; off <<= 1) {
              prr[r] += __shfl_xor(prr[r], off, 16);
              pii[r] += __shfl_xor(pii[r], off, 16);
            }
            prr[r] += bpR;
            pii[r] += bpI;
          }
          if (n < 8) {
            const int r = n >> 1, c = n & 1;
            const float num = c ? pii[r] : prr[r];
            const int rp = r ^ 1;
            const float n2 = prr[r] * prr[r] + pii[r] * pii[r] +
                             prr[rp] * prr[rp] + pii[rp] * pii[rp];
            p.out[g0 * 16 + (4 * q + r) * 2 + c] = num / sqrtf(n2);
          }
        }
      }
    }
  }
}

extern "C" void kernel_launch(void* const* d_in, const int* in_sizes, int n_in,
                              void* d_out, int out_size, void* d_ws, size_t ws_size,
                              hipStream_t stream) {
  Params p;
  p.ap    = (const float*)d_in[0];
  p.ef    = (const float*)d_in[1];
  p.wpa   = (const float*)d_in[2];  p.bpa   = (const float*)d_in[3];
  p.wpe   = (const float*)d_in[4];  p.bpe   = (const float*)d_in[5];
  p.w51   = (const float*)d_in[6];  p.b51   = (const float*)d_in[7];
  p.w52   = (const float*)d_in[8];  p.b52   = (const float*)d_in[9];
  p.w53   = (const float*)d_in[10]; p.b53   = (const float*)d_in[11];
  p.w61   = (const float*)d_in[12]; p.b61   = (const float*)d_in[13];
  p.w62   = (const float*)d_in[14]; p.b62   = (const float*)d_in[15];
  p.w63   = (const float*)d_in[16]; p.b63   = (const float*)d_in[17];
  p.w71   = (const float*)d_in[18]; p.b71   = (const float*)d_in[19];
  p.w72   = (const float*)d_in[20]; p.b72   = (const float*)d_in[21];
  p.w73   = (const float*)d_in[22]; p.b73   = (const float*)d_in[23];
  p.wpost = (const float*)d_in[24]; p.bpost = (const float*)d_in[25];
  p.out   = (float*)d_out;
  p.ws    = (u16*)d_ws;
  p.gtot  = in_sizes[0] / 4;  // G from ap_feat [G,B,1]

  hipLaunchKernelGGL(swizzle_weights, dim3(96), dim3(64), 0, stream, p);
  hipLaunchKernelGGL(hetgnn_mfma, dim3(NBLK), dim3(256), 0, stream, p);
}

// Round 4
// 296.105 us; speedup vs baseline: 5.2551x; 1.3132x over previous
//
#include <hip/hip_runtime.h>

// HetGNN fused kernel, round 4: MFMA structure from round 3 (verified correct)
// + register-pressure fix. Round-3 counters showed 146 MB WRITE / 471 MB FETCH
// per dispatch = scratch spill/fill traffic (kernel only legitimately writes
// ~1.2 MB); spills sat inside the serial layer chain -> 80% idle.
// Changes:
//  - all persistent per-lane constants (9 bias vecs, b61, wpost/bpost,
//    wpa/bpa/wpe/bpe) moved to a small block-shared LDS table, read at use
//    (wave-uniform-per-quad broadcast reads, conflict-free).
//  - epilogue dynamic array indexing replaced by cndmask select (sel4).
//  - one __syncthreads() after staging; waves otherwise independent.
// LDS 68.3 KB -> still 2 blocks/CU.

typedef unsigned short u16;
typedef unsigned int   u32;
typedef __attribute__((ext_vector_type(8))) short short8_t;
typedef __attribute__((ext_vector_type(4))) float floatx4;

// u16 offsets of each matrix's fragment block inside d_ws.
#define OFF_W51 0
#define OFF_W61 8192
#define OFF_W71 16384
#define OFF_W52 24576
#define OFF_W53 28672
#define OFF_W62 32768
#define OFF_W63 36864
#define OFF_W72 40960
#define OFF_W73 45056

// f32 offsets inside the sConst LDS table.
#define CB51 0
#define CB52 64
#define CB53 128
#define CB61 192
#define CB62 256
#define CB63 320
#define CB71 384
#define CB72 448
#define CB73 512
#define CWPO 576   // wpost [64][2]
#define CBPO 704   // bpost [2]
#define CWPA 768   // w_pre_ap [64]
#define CBPA 832   // b_pre_ap [64]
#define CWPE 896   // w_pre_edge [2][64]
#define CBPE 1024  // b_pre_edge [64]
#define CSZ  1088

struct Params {
  const float *ap, *ef;
  const float *wpa, *bpa, *wpe, *bpe;
  const float *w51, *b51, *w52, *b52, *w53, *b53;
  const float *w61, *b61, *w62, *b62, *w63, *b63;
  const float *w71, *b71, *w72, *b72, *w73, *b73;
  const float *wpost, *bpost;
  float *out;
  u16 *ws;
  int gtot;
};

__device__ __forceinline__ u16 f2bf(float f) {
  u32 x = __float_as_uint(f);
  return (u16)((x + 0x7fff + ((x >> 16) & 1)) >> 16);  // RNE
}
__device__ __forceinline__ u32 pk2(float a, float b) {
  return (u32)f2bf(a) | ((u32)f2bf(b) << 16);
}
__device__ __forceinline__ float sel4(int i, float x0, float x1, float x2, float x3) {
  const float lo = (i & 1) ? x1 : x0;
  const float hi = (i & 1) ? x3 : x2;
  return (i & 2) ? hi : lo;
}

// ---------------- setup: swizzle all 9 weight mats into B-frag order ----------------
__global__ void swizzle_weights(Params p) {
  const float* mats[9] = {p.w51, p.w61, p.w71, p.w52, p.w53, p.w62, p.w63, p.w72, p.w73};
  const int fi = blockIdx.x;   // 0..95
  const int l  = threadIdx.x;  // 0..63
  const float* W;
  int t, h;
  if (fi < 48) { W = mats[fi >> 4]; const int loc = fi & 15; t = loc >> 2; h = loc & 3; }
  else { const int j = fi - 48; W = mats[3 + (j >> 3)]; const int loc = j & 7; t = loc >> 1; h = loc & 1; }
  const int n  = 16 * t + (l & 15);
  const int k0 = 32 * h + (l >> 4) * 8;
  u16* dst = p.ws + fi * 512 + l * 8;
#pragma unroll
  for (int j = 0; j < 8; ++j) dst[j] = f2bf(W[(k0 + j) * 64 + n]);
}

// ---------------- main kernel helpers ----------------
__device__ __forceinline__ floatx4 mfma16(short8_t a, short8_t b, floatx4 c) {
  return __builtin_amdgcn_mfma_f32_16x16x32_bf16(a, b, c, 0, 0, 0);
}

template<int TSTRIDE>
__device__ __forceinline__ void layerK64(floatx4* acc, const u16* A, const u16* B, int l) {
  const short8_t a0 = *(const short8_t*)(A + l * 8);
  const short8_t a1 = *(const short8_t*)(A + 512 + l * 8);
#pragma unroll
  for (int t = 0; t < 4; ++t) {
    const short8_t b0 = *(const short8_t*)(B + (t * TSTRIDE + 0) * 512 + l * 8);
    const short8_t b1 = *(const short8_t*)(B + (t * TSTRIDE + 1) * 512 + l * 8);
    acc[t] = mfma16(a0, b0, acc[t]);
    acc[t] = mfma16(a1, b1, acc[t]);
  }
}

__device__ __forceinline__ void layerK128(floatx4* acc, const u16* A0, const u16* A1,
                                          const u16* B, int l) {
  short8_t a[4];
  a[0] = *(const short8_t*)(A0 + l * 8);
  a[1] = *(const short8_t*)(A0 + 512 + l * 8);
  a[2] = *(const short8_t*)(A1 + l * 8);
  a[3] = *(const short8_t*)(A1 + 512 + l * 8);
#pragma unroll
  for (int t = 0; t < 4; ++t)
#pragma unroll
    for (int h = 0; h < 4; ++h)
      acc[t] = mfma16(a[h], *(const short8_t*)(B + (t * 4 + h) * 512 + l * 8), acc[t]);
}

// C-layout regs -> A-frag-swizzled bf16 LDS (with relu). Element (m=4q+r, k=16t+n).
__device__ __forceinline__ void scatter_relu_bf16(u16* dst, const floatx4* acc, int q, int n) {
#pragma unroll
  for (int t = 0; t < 4; ++t) {
    const int kk = (t & 1) * 2 + (n >> 3);
    u16* base = dst + (t >> 1) * 512 + (n & 7);
#pragma unroll
    for (int r = 0; r < 4; ++r)
      base[(4 * q + r + 16 * kk) * 8] = f2bf(fmaxf(acc[t][r], 0.f));
  }
}

__device__ __forceinline__ void scatter_f32(float* dst, const floatx4* acc, int q, int n) {
#pragma unroll
  for (int t = 0; t < 4; ++t) {
    const int kk = (t & 1) * 2 + (n >> 3);
    float* base = dst + (t >> 1) * 512 + (n & 7);
#pragma unroll
    for (int r = 0; r < 4; ++r)
      base[(4 * q + r + 16 * kk) * 8] = acc[t][r];
  }
}

// bias init from LDS table: bias[16t+n], wave-uniform per (t, n) -> broadcast.
__device__ __forceinline__ void init_accL(floatx4* acc, const float* cb, int n) {
#pragma unroll
  for (int t = 0; t < 4; ++t) {
    const float b = cb[16 * t + n];
    floatx4 v; v[0] = b; v[1] = b; v[2] = b; v[3] = b;
    acc[t] = v;
  }
}

#define NBLK 512
#define PPW  4   // 512 blk * 4 waves * 4 pairs = 8192 pairs = 16384 graphs

__global__ __launch_bounds__(256, 2) void hetgnn_mfma(Params p) {
  __shared__ __align__(16) u16   sB[4][4096];   // 32 KB: Ab,Eb,T1,T2 per wave
  __shared__ __align__(16) float sF[4][2048];   // 32 KB: aP,eP per wave
  __shared__ __align__(16) float sConst[CSZ];   // 4.3 KB: biases + small mats

  const int tid  = threadIdx.x;
  const int wave = tid >> 6;
  const int l    = tid & 63;
  const int q    = l >> 4;
  const int n    = l & 15;

  // ---- stage constants into LDS ----
  if (tid < 64) {
    sConst[CB51 + tid] = p.b51[tid];
    sConst[CB52 + tid] = p.b52[tid];
    sConst[CB53 + tid] = p.b53[tid];
    sConst[CB61 + tid] = p.b61[tid];
    sConst[CB62 + tid] = p.b62[tid];
    sConst[CB63 + tid] = p.b63[tid];
    sConst[CB71 + tid] = p.b71[tid];
    sConst[CB72 + tid] = p.b72[tid];
    sConst[CB73 + tid] = p.b73[tid];
    sConst[CWPA + tid] = p.wpa[tid];
    sConst[CBPA + tid] = p.bpa[tid];
    sConst[CBPE + tid] = p.bpe[tid];
  }
  if (tid < 128) {
    sConst[CWPO + tid] = p.wpost[tid];
    sConst[CWPE + tid] = p.wpe[tid];
  }
  if (tid < 2) sConst[CBPO + tid] = p.bpost[tid];
  __syncthreads();

  u16* Ab = sB[wave];
  u16* Eb = Ab + 1024;
  u16* T1 = Ab + 2048;
  u16* T2 = Ab + 3072;
  float* aP = sF[wave];
  float* eP = aP + 1024;

  const u16* ws = p.ws;
  const int wslot = blockIdx.x * 4 + wave;

  for (int pi = 0; pi < PPW; ++pi) {
    const int g0 = (wslot * PPW + pi) * 2;   // 2 graphs: g0, g0+1
    if (g0 + 2 > p.gtot) break;

    // ---------------- pre-layer: fill Ab (a rows) + Eb, A-frag-swizzled ----------------
    {
      const float apv = p.ap[(g0 + (n >> 3)) * 4 + ((n >> 1) & 3)];
      const float f0  = p.ef[(g0 + (n >> 3)) * 16 + (n & 7) * 2];
      const float f1  = p.ef[(g0 + (n >> 3)) * 16 + (n & 7) * 2 + 1];
#pragma unroll
      for (int h = 0; h < 2; ++h) {
        const int fb = 32 * h + 8 * q;
        const float4 wa0 = *(const float4*)(sConst + CWPA + fb);
        const float4 wa1 = *(const float4*)(sConst + CWPA + fb + 4);
        const float4 ba0 = *(const float4*)(sConst + CBPA + fb);
        const float4 ba1 = *(const float4*)(sConst + CBPA + fb + 4);
        uint4 pa;
        pa.x = pk2(fmaxf(fmaf(apv, wa0.x, ba0.x), 0.f), fmaxf(fmaf(apv, wa0.y, ba0.y), 0.f));
        pa.y = pk2(fmaxf(fmaf(apv, wa0.z, ba0.z), 0.f), fmaxf(fmaf(apv, wa0.w, ba0.w), 0.f));
        pa.z = pk2(fmaxf(fmaf(apv, wa1.x, ba1.x), 0.f), fmaxf(fmaf(apv, wa1.y, ba1.y), 0.f));
        pa.w = pk2(fmaxf(fmaf(apv, wa1.z, ba1.z), 0.f), fmaxf(fmaf(apv, wa1.w, ba1.w), 0.f));
        *(uint4*)(Ab + h * 512 + l * 8) = pa;

        const float4 w00 = *(const float4*)(sConst + CWPE + fb);
        const float4 w01 = *(const float4*)(sConst + CWPE + fb + 4);
        const float4 w10 = *(const float4*)(sConst + CWPE + 64 + fb);
        const float4 w11 = *(const float4*)(sConst + CWPE + 64 + fb + 4);
        const float4 be0 = *(const float4*)(sConst + CBPE + fb);
        const float4 be1 = *(const float4*)(sConst + CBPE + fb + 4);
        uint4 pe;
        pe.x = pk2(fmaxf(fmaf(f0, w00.x, fmaf(f1, w10.x, be0.x)), 0.f),
                   fmaxf(fmaf(f0, w00.y, fmaf(f1, w10.y, be0.y)), 0.f));
        pe.y = pk2(fmaxf(fmaf(f0, w00.z, fmaf(f1, w10.z, be0.z)), 0.f),
                   fmaxf(fmaf(f0, w00.w, fmaf(f1, w10.w, be0.w)), 0.f));
        pe.z = pk2(fmaxf(fmaf(f0, w01.x, fmaf(f1, w11.x, be1.x)), 0.f),
                   fmaxf(fmaf(f0, w01.y, fmaf(f1, w11.y, be1.y)), 0.f));
        pe.w = pk2(fmaxf(fmaf(f0, w01.z, fmaf(f1, w11.z, be1.z)), 0.f),
                   fmaxf(fmaf(f0, w01.w, fmaf(f1, w11.w, be1.w)), 0.f));
        *(uint4*)(Eb + h * 512 + l * 8) = pe;
      }
    }

    // ---------------- 2 shared-weight update iterations ----------------
#pragma unroll 1
    for (int it = 0; it < 2; ++it) {
      // ---- mlp5 -> m1 (C-layout regs) ----
      floatx4 m1[4];
      {
        floatx4 acc[4]; init_accL(acc, sConst + CB51, n);
        layerK128(acc, Ab, Eb, ws + OFF_W51, l);
        scatter_relu_bf16(T1, acc, q, n);
        floatx4 acc2[4]; init_accL(acc2, sConst + CB52, n);
        layerK64<2>(acc2, T1, ws + OFF_W52, l);
        scatter_relu_bf16(T2, acc2, q, n);
        floatx4 acc3[4]; init_accL(acc3, sConst + CB53, n);
        layerK64<2>(acc3, T2, ws + OFF_W53, l);
#pragma unroll
        for (int t = 0; t < 4; ++t)
#pragma unroll
          for (int r = 0; r < 4; ++r) m1[t][r] = fmaxf(acc3[t][r], 0.f);
      }

      // ---- mlp6 -> m2 (masked running max, C-layout regs) ----
      floatx4 m2[4];
#pragma unroll
      for (int t = 0; t < 4; ++t) { m2[t][0] = -1e30f; m2[t][1] = -1e30f; m2[t][2] = -1e30f; m2[t][3] = -1e30f; }
      {
        floatx4 accA[4];
#pragma unroll
        for (int t = 0; t < 4; ++t) { accA[t][0] = 0.f; accA[t][1] = 0.f; accA[t][2] = 0.f; accA[t][3] = 0.f; }
        layerK64<4>(accA, Ab, ws + OFF_W61, l);
        scatter_f32(aP, accA, q, n);
        floatx4 accE[4];
#pragma unroll
        for (int t = 0; t < 4; ++t) { accE[t][0] = 0.f; accE[t][1] = 0.f; accE[t][2] = 0.f; accE[t][3] = 0.f; }
        layerK64<4>(accE, Eb, ws + OFF_W61 + 2 * 512, l);
        scatter_f32(eP, accE, q, n);

#pragma unroll 1
        for (int bp = 0; bp < 4; ++bp) {
#pragma unroll
          for (int h = 0; h < 2; ++h) {
            const float* apc = aP + (h * 64 + l) * 8;
            const int re = (n & 8) + bp * 2 + (n & 1);
            const float* epc = eP + (h * 64 + re + (l & 48)) * 8;
            const float4 a0 = *(const float4*)apc;
            const float4 a1 = *(const float4*)(apc + 4);
            const float4 e0 = *(const float4*)epc;
            const float4 e1 = *(const float4*)(epc + 4);
            const float4 b0 = *(const float4*)(sConst + CB61 + 32 * h + 8 * q);
            const float4 b1 = *(const float4*)(sConst + CB61 + 32 * h + 8 * q + 4);
            uint4 ph;
            ph.x = pk2(fmaxf(a0.x + e0.x + b0.x, 0.f), fmaxf(a0.y + e0.y + b0.y, 0.f));
            ph.y = pk2(fmaxf(a0.z + e0.z + b0.z, 0.f), fmaxf(a0.w + e0.w + b0.w, 0.f));
            ph.z = pk2(fmaxf(a1.x + e1.x + b1.x, 0.f), fmaxf(a1.y + e1.y + b1.y, 0.f));
            ph.w = pk2(fmaxf(a1.z + e1.z + b1.z, 0.f), fmaxf(a1.w + e1.w + b1.w, 0.f));
            *(uint4*)(T1 + h * 512 + l * 8) = ph;
          }
          floatx4 acc2[4]; init_accL(acc2, sConst + CB62, n);
          layerK64<2>(acc2, T1, ws + OFF_W62, l);
          scatter_relu_bf16(T2, acc2, q, n);
          floatx4 acc3[4]; init_accL(acc3, sConst + CB63, n);
          layerK64<2>(acc3, T2, ws + OFF_W63, l);
#pragma unroll
          for (int t = 0; t < 4; ++t)
#pragma unroll
            for (int r = 0; r < 4; ++r) {
              const float v = fmaxf(acc3[t][r], 0.f);
              const int b = ((4 * q + r) >> 1) & 3;
              if (b != bp) m2[t][r] = fmaxf(m2[t][r], v);
            }
        }
      }

      // ---- agg (regs) + mlp7 ----
      {
        floatx4 ag[4];
#pragma unroll
        for (int t = 0; t < 4; ++t) {
          ag[t][0] = fmaxf(m1[t][1], m2[t][0]);
          ag[t][1] = fmaxf(m1[t][0], m2[t][1]);
          ag[t][2] = fmaxf(m1[t][3], m2[t][2]);
          ag[t][3] = fmaxf(m1[t][2], m2[t][3]);
        }
        scatter_relu_bf16(T1, ag, q, n);
        floatx4 acc[4]; init_accL(acc, sConst + CB71, n);
        layerK128(acc, T1, Eb, ws + OFF_W71, l);
        scatter_relu_bf16(T2, acc, q, n);
        floatx4 acc2[4]; init_accL(acc2, sConst + CB72, n);
        layerK64<2>(acc2, T2, ws + OFF_W72, l);
        scatter_relu_bf16(T1, acc2, q, n);
        floatx4 acc3[4]; init_accL(acc3, sConst + CB73, n);
        layerK64<2>(acc3, T1, ws + OFF_W73, l);

        if (it == 0) {
          scatter_relu_bf16(Eb, acc3, q, n);
        } else {
          // ---- post linear + per-(g,b) L2 row normalization ----
          float prr[4] = {0.f, 0.f, 0.f, 0.f}, pii[4] = {0.f, 0.f, 0.f, 0.f};
#pragma unroll
          for (int t = 0; t < 4; ++t) {
            const float wr = sConst[CWPO + (16 * t + n) * 2];
            const float wi = sConst[CWPO + (16 * t + n) * 2 + 1];
#pragma unroll
            for (int r = 0; r < 4; ++r) {
              const float e = fmaxf(acc3[t][r], 0.f);
              prr[r] = fmaf(e, wr, prr[r]);
              pii[r] = fmaf(e, wi, pii[r]);
            }
          }
          const float bpR = sConst[CBPO], bpI = sConst[CBPO + 1];
#pragma unroll
          for (int r = 0; r < 4; ++r) {
#pragma unroll
            for (int off = 1; off < 16; off <<= 1) {
              prr[r] += __shfl_xor(prr[r], off, 16);
              pii[r] += __shfl_xor(pii[r], off, 16);
            }
            prr[r] += bpR;
            pii[r] += bpI;
          }
          const int r = n >> 1, c = n & 1, rp = r ^ 1;
          const float pr_r  = sel4(r,  prr[0], prr[1], prr[2], prr[3]);
          const float pi_r  = sel4(r,  pii[0], pii[1], pii[2], pii[3]);
          const float pr_rp = sel4(rp, prr[0], prr[1], prr[2], prr[3]);
          const float pi_rp = sel4(rp, pii[0], pii[1], pii[2], pii[3]);
          const float num = c ? pi_r : pr_r;
          const float n2  = pr_r * pr_r + pi_r * pi_r + pr_rp * pr_rp + pi_rp * pi_rp;
          if (n < 8) p.out[g0 * 16 + (4 * q + r) * 2 + c] = num / sqrtf(n2);
        }
      }
    }
  }
}

extern "C" void kernel_launch(void* const* d_in, const int* in_sizes, int n_in,
                              void* d_out, int out_size, void* d_ws, size_t ws_size,
                              hipStream_t stream) {
  Params p;
  p.ap    = (const float*)d_in[0];
  p.ef    = (const float*)d_in[1];
  p.wpa   = (const float*)d_in[2];  p.bpa   = (const float*)d_in[3];
  p.wpe   = (const float*)d_in[4];  p.bpe   = (const float*)d_in[5];
  p.w51   = (const float*)d_in[6];  p.b51   = (const float*)d_in[7];
  p.w52   = (const float*)d_in[8];  p.b52   = (const float*)d_in[9];
  p.w53   = (const float*)d_in[10]; p.b53   = (const float*)d_in[11];
  p.w61   = (const float*)d_in[12]; p.b61   = (const float*)d_in[13];
  p.w62   = (const float*)d_in[14]; p.b62   = (const float*)d_in[15];
  p.w63   = (const float*)d_in[16]; p.b63   = (const float*)d_in[17];
  p.w71   = (const float*)d_in[18]; p.b71   = (const float*)d_in[19];
  p.w72   = (const float*)d_in[20]; p.b72   = (const float*)d_in[21];
  p.w73   = (const float*)d_in[22]; p.b73   = (const float*)d_in[23];
  p.wpost = (const float*)d_in[24]; p.bpost = (const float*)d_in[25];
  p.out   = (float*)d_out;
  p.ws    = (u16*)d_ws;
  p.gtot  = in_sizes[0] / 4;  // G from ap_feat [G,B,1]

  hipLaunchKernelGGL(swizzle_weights, dim3(96), dim3(64), 0, stream, p);
  hipLaunchKernelGGL(hetgnn_mfma, dim3(NBLK), dim3(256), 0, stream, p);
}

// Round 5
// 288.381 us; speedup vs baseline: 5.3959x; 1.0268x over previous
//
#include <hip/hip_runtime.h>

// HetGNN fused kernel, round 5: kill the residual scratch spill/fill.
// Round-4 counters: WRITE 67.5 MB vs ~1.2 MB legit => still spilling;
// VGPR_Count pinned at 128; FETCH:WRITE 3.7:1 => spilled m1/m2 refilled
// per bp-iteration. Changes vs round 4 (everything else identical):
//  1. __attribute__((amdgpu_waves_per_eu(2,2))): pin 2 waves/EU => 256-reg
//     budget, matching the LDS-limited occupancy (70 KB -> 2 blocks/CU).
//  2. m1/m2 kept as packed bf16 pairs (8 u32 regs each, was 16 f32 each);
//     running masked max via v_pk_max_i16 (relu'd bf16 >= 0 compares as
//     int16; init 0 == init -1e30). Numerically identical to round 4:
//     RNE rounding is monotone, so max-then-round == round-then-max, and
//     agg already passed through bf16 at the scatter.

typedef unsigned short u16;
typedef unsigned int   u32;
typedef __attribute__((ext_vector_type(8))) short short8_t;
typedef __attribute__((ext_vector_type(2))) short short2v;
typedef __attribute__((ext_vector_type(4))) float floatx4;

// u16 offsets of each matrix's fragment block inside d_ws.
#define OFF_W51 0
#define OFF_W61 8192
#define OFF_W71 16384
#define OFF_W52 24576
#define OFF_W53 28672
#define OFF_W62 32768
#define OFF_W63 36864
#define OFF_W72 40960
#define OFF_W73 45056

// f32 offsets inside the sConst LDS table.
#define CB51 0
#define CB52 64
#define CB53 128
#define CB61 192
#define CB62 256
#define CB63 320
#define CB71 384
#define CB72 448
#define CB73 512
#define CWPO 576   // wpost [64][2]
#define CBPO 704   // bpost [2]
#define CWPA 768   // w_pre_ap [64]
#define CBPA 832   // b_pre_ap [64]
#define CWPE 896   // w_pre_edge [2][64]
#define CBPE 1024  // b_pre_edge [64]
#define CSZ  1088

struct Params {
  const float *ap, *ef;
  const float *wpa, *bpa, *wpe, *bpe;
  const float *w51, *b51, *w52, *b52, *w53, *b53;
  const float *w61, *b61, *w62, *b62, *w63, *b63;
  const float *w71, *b71, *w72, *b72, *w73, *b73;
  const float *wpost, *bpost;
  float *out;
  u16 *ws;
  int gtot;
};

__device__ __forceinline__ u16 f2bf(float f) {
  u32 x = __float_as_uint(f);
  return (u16)((x + 0x7fff + ((x >> 16) & 1)) >> 16);  // RNE
}
__device__ __forceinline__ u32 pk2(float a, float b) {
  return (u32)f2bf(a) | ((u32)f2bf(b) << 16);
}
// packed max of two bf16 pairs; valid for non-negative bf16 (int16-monotone).
__device__ __forceinline__ u32 pkmax(u32 a, u32 b) {
  const short2v r = __builtin_elementwise_max(__builtin_bit_cast(short2v, a),
                                              __builtin_bit_cast(short2v, b));
  return __builtin_bit_cast(u32, r);
}
__device__ __forceinline__ u32 ror16(u32 x) { return (x >> 16) | (x << 16); }
__device__ __forceinline__ float sel4(int i, float x0, float x1, float x2, float x3) {
  const float lo = (i & 1) ? x1 : x0;
  const float hi = (i & 1) ? x3 : x2;
  return (i & 2) ? hi : lo;
}

// ---------------- setup: swizzle all 9 weight mats into B-frag order ----------------
__global__ void swizzle_weights(Params p) {
  const float* mats[9] = {p.w51, p.w61, p.w71, p.w52, p.w53, p.w62, p.w63, p.w72, p.w73};
  const int fi = blockIdx.x;   // 0..95
  const int l  = threadIdx.x;  // 0..63
  const float* W;
  int t, h;
  if (fi < 48) { W = mats[fi >> 4]; const int loc = fi & 15; t = loc >> 2; h = loc & 3; }
  else { const int j = fi - 48; W = mats[3 + (j >> 3)]; const int loc = j & 7; t = loc >> 1; h = loc & 1; }
  const int n  = 16 * t + (l & 15);
  const int k0 = 32 * h + (l >> 4) * 8;
  u16* dst = p.ws + fi * 512 + l * 8;
#pragma unroll
  for (int j = 0; j < 8; ++j) dst[j] = f2bf(W[(k0 + j) * 64 + n]);
}

// ---------------- main kernel helpers ----------------
__device__ __forceinline__ floatx4 mfma16(short8_t a, short8_t b, floatx4 c) {
  return __builtin_amdgcn_mfma_f32_16x16x32_bf16(a, b, c, 0, 0, 0);
}

template<int TSTRIDE>
__device__ __forceinline__ void layerK64(floatx4* acc, const u16* A, const u16* B, int l) {
  const short8_t a0 = *(const short8_t*)(A + l * 8);
  const short8_t a1 = *(const short8_t*)(A + 512 + l * 8);
#pragma unroll
  for (int t = 0; t < 4; ++t) {
    const short8_t b0 = *(const short8_t*)(B + (t * TSTRIDE + 0) * 512 + l * 8);
    const short8_t b1 = *(const short8_t*)(B + (t * TSTRIDE + 1) * 512 + l * 8);
    acc[t] = mfma16(a0, b0, acc[t]);
    acc[t] = mfma16(a1, b1, acc[t]);
  }
}

__device__ __forceinline__ void layerK128(floatx4* acc, const u16* A0, const u16* A1,
                                          const u16* B, int l) {
  short8_t a[4];
  a[0] = *(const short8_t*)(A0 + l * 8);
  a[1] = *(const short8_t*)(A0 + 512 + l * 8);
  a[2] = *(const short8_t*)(A1 + l * 8);
  a[3] = *(const short8_t*)(A1 + 512 + l * 8);
#pragma unroll
  for (int t = 0; t < 4; ++t)
#pragma unroll
    for (int h = 0; h < 4; ++h)
      acc[t] = mfma16(a[h], *(const short8_t*)(B + (t * 4 + h) * 512 + l * 8), acc[t]);
}

// C-layout regs -> A-frag-swizzled bf16 LDS (with relu). Element (m=4q+r, k=16t+n).
__device__ __forceinline__ void scatter_relu_bf16(u16* dst, const floatx4* acc, int q, int n) {
#pragma unroll
  for (int t = 0; t < 4; ++t) {
    const int kk = (t & 1) * 2 + (n >> 3);
    u16* base = dst + (t >> 1) * 512 + (n & 7);
#pragma unroll
    for (int r = 0; r < 4; ++r)
      base[(4 * q + r + 16 * kk) * 8] = f2bf(fmaxf(acc[t][r], 0.f));
  }
}

// Packed-bf16 variant: src[2t+half] holds rows (4q+2*half, 4q+2*half+1).
__device__ __forceinline__ void scatter_pk(u16* dst, const u32* src, int q, int n) {
#pragma unroll
  for (int t = 0; t < 4; ++t) {
    const int kk = (t & 1) * 2 + (n >> 3);
    u16* base = dst + (t >> 1) * 512 + (n & 7);
#pragma unroll
    for (int half = 0; half < 2; ++half) {
      const u32 v = src[2 * t + half];
      base[(4 * q + 2 * half + 0 + 16 * kk) * 8] = (u16)v;
      base[(4 * q + 2 * half + 1 + 16 * kk) * 8] = (u16)(v >> 16);
    }
  }
}

__device__ __forceinline__ void scatter_f32(float* dst, const floatx4* acc, int q, int n) {
#pragma unroll
  for (int t = 0; t < 4; ++t) {
    const int kk = (t & 1) * 2 + (n >> 3);
    float* base = dst + (t >> 1) * 512 + (n & 7);
#pragma unroll
    for (int r = 0; r < 4; ++r)
      base[(4 * q + r + 16 * kk) * 8] = acc[t][r];
  }
}

__device__ __forceinline__ void init_accL(floatx4* acc, const float* cb, int n) {
#pragma unroll
  for (int t = 0; t < 4; ++t) {
    const float b = cb[16 * t + n];
    floatx4 v; v[0] = b; v[1] = b; v[2] = b; v[3] = b;
    acc[t] = v;
  }
}

#define NBLK 512
#define PPW  4   // 512 blk * 4 waves * 4 pairs = 8192 pairs = 16384 graphs

__global__ __launch_bounds__(256)
__attribute__((amdgpu_waves_per_eu(2, 2)))
void hetgnn_mfma(Params p) {
  __shared__ __align__(16) u16   sB[4][4096];   // 32 KB: Ab,Eb,T1,T2 per wave
  __shared__ __align__(16) float sF[4][2048];   // 32 KB: aP,eP per wave
  __shared__ __align__(16) float sConst[CSZ];   // 4.3 KB: biases + small mats

  const int tid  = threadIdx.x;
  const int wave = tid >> 6;
  const int l    = tid & 63;
  const int q    = l >> 4;
  const int n    = l & 15;

  // ---- stage constants into LDS ----
  if (tid < 64) {
    sConst[CB51 + tid] = p.b51[tid];
    sConst[CB52 + tid] = p.b52[tid];
    sConst[CB53 + tid] = p.b53[tid];
    sConst[CB61 + tid] = p.b61[tid];
    sConst[CB62 + tid] = p.b62[tid];
    sConst[CB63 + tid] = p.b63[tid];
    sConst[CB71 + tid] = p.b71[tid];
    sConst[CB72 + tid] = p.b72[tid];
    sConst[CB73 + tid] = p.b73[tid];
    sConst[CWPA + tid] = p.wpa[tid];
    sConst[CBPA + tid] = p.bpa[tid];
    sConst[CBPE + tid] = p.bpe[tid];
  }
  if (tid < 128) {
    sConst[CWPO + tid] = p.wpost[tid];
    sConst[CWPE + tid] = p.wpe[tid];
  }
  if (tid < 2) sConst[CBPO + tid] = p.bpost[tid];
  __syncthreads();

  u16* Ab = sB[wave];
  u16* Eb = Ab + 1024;
  u16* T1 = Ab + 2048;
  u16* T2 = Ab + 3072;
  float* aP = sF[wave];
  float* eP = aP + 1024;

  const u16* ws = p.ws;
  const int wslot = blockIdx.x * 4 + wave;

  for (int pi = 0; pi < PPW; ++pi) {
    const int g0 = (wslot * PPW + pi) * 2;   // 2 graphs: g0, g0+1
    if (g0 + 2 > p.gtot) break;

    // ---------------- pre-layer: fill Ab (a rows) + Eb, A-frag-swizzled ----------------
    {
      const float apv = p.ap[(g0 + (n >> 3)) * 4 + ((n >> 1) & 3)];
      const float f0  = p.ef[(g0 + (n >> 3)) * 16 + (n & 7) * 2];
      const float f1  = p.ef[(g0 + (n >> 3)) * 16 + (n & 7) * 2 + 1];
#pragma unroll
      for (int h = 0; h < 2; ++h) {
        const int fb = 32 * h + 8 * q;
        const float4 wa0 = *(const float4*)(sConst + CWPA + fb);
        const float4 wa1 = *(const float4*)(sConst + CWPA + fb + 4);
        const float4 ba0 = *(const float4*)(sConst + CBPA + fb);
        const float4 ba1 = *(const float4*)(sConst + CBPA + fb + 4);
        uint4 pa;
        pa.x = pk2(fmaxf(fmaf(apv, wa0.x, ba0.x), 0.f), fmaxf(fmaf(apv, wa0.y, ba0.y), 0.f));
        pa.y = pk2(fmaxf(fmaf(apv, wa0.z, ba0.z), 0.f), fmaxf(fmaf(apv, wa0.w, ba0.w), 0.f));
        pa.z = pk2(fmaxf(fmaf(apv, wa1.x, ba1.x), 0.f), fmaxf(fmaf(apv, wa1.y, ba1.y), 0.f));
        pa.w = pk2(fmaxf(fmaf(apv, wa1.z, ba1.z), 0.f), fmaxf(fmaf(apv, wa1.w, ba1.w), 0.f));
        *(uint4*)(Ab + h * 512 + l * 8) = pa;

        const float4 w00 = *(const float4*)(sConst + CWPE + fb);
        const float4 w01 = *(const float4*)(sConst + CWPE + fb + 4);
        const float4 w10 = *(const float4*)(sConst + CWPE + 64 + fb);
        const float4 w11 = *(const float4*)(sConst + CWPE + 64 + fb + 4);
        const float4 be0 = *(const float4*)(sConst + CBPE + fb);
        const float4 be1 = *(const float4*)(sConst + CBPE + fb + 4);
        uint4 pe;
        pe.x = pk2(fmaxf(fmaf(f0, w00.x, fmaf(f1, w10.x, be0.x)), 0.f),
                   fmaxf(fmaf(f0, w00.y, fmaf(f1, w10.y, be0.y)), 0.f));
        pe.y = pk2(fmaxf(fmaf(f0, w00.z, fmaf(f1, w10.z, be0.z)), 0.f),
                   fmaxf(fmaf(f0, w00.w, fmaf(f1, w10.w, be0.w)), 0.f));
        pe.z = pk2(fmaxf(fmaf(f0, w01.x, fmaf(f1, w11.x, be1.x)), 0.f),
                   fmaxf(fmaf(f0, w01.y, fmaf(f1, w11.y, be1.y)), 0.f));
        pe.w = pk2(fmaxf(fmaf(f0, w01.z, fmaf(f1, w11.z, be1.z)), 0.f),
                   fmaxf(fmaf(f0, w01.w, fmaf(f1, w11.w, be1.w)), 0.f));
        *(uint4*)(Eb + h * 512 + l * 8) = pe;
      }
    }

    // ---------------- 2 shared-weight update iterations ----------------
#pragma unroll 1
    for (int it = 0; it < 2; ++it) {
      // ---- mlp5 -> m1 (packed bf16 pairs: m1p[2t+half] = rows 4q+2half(+1)) ----
      u32 m1p[8];
      {
        floatx4 acc[4]; init_accL(acc, sConst + CB51, n);
        layerK128(acc, Ab, Eb, ws + OFF_W51, l);
        scatter_relu_bf16(T1, acc, q, n);
        floatx4 acc2[4]; init_accL(acc2, sConst + CB52, n);
        layerK64<2>(acc2, T1, ws + OFF_W52, l);
        scatter_relu_bf16(T2, acc2, q, n);
        floatx4 acc3[4]; init_accL(acc3, sConst + CB53, n);
        layerK64<2>(acc3, T2, ws + OFF_W53, l);
#pragma unroll
        for (int t = 0; t < 4; ++t) {
          m1p[2 * t + 0] = pk2(fmaxf(acc3[t][0], 0.f), fmaxf(acc3[t][1], 0.f));
          m1p[2 * t + 1] = pk2(fmaxf(acc3[t][2], 0.f), fmaxf(acc3[t][3], 0.f));
        }
      }

      // ---- mlp6 -> m2 (masked running max, packed bf16; init 0 valid: relu'd >= 0) ----
      u32 m2p[8];
#pragma unroll
      for (int i = 0; i < 8; ++i) m2p[i] = 0u;
      {
        floatx4 accA[4];
#pragma unroll
        for (int t = 0; t < 4; ++t) { accA[t][0] = 0.f; accA[t][1] = 0.f; accA[t][2] = 0.f; accA[t][3] = 0.f; }
        layerK64<4>(accA, Ab, ws + OFF_W61, l);
        scatter_f32(aP, accA, q, n);
        floatx4 accE[4];
#pragma unroll
        for (int t = 0; t < 4; ++t) { accE[t][0] = 0.f; accE[t][1] = 0.f; accE[t][2] = 0.f; accE[t][3] = 0.f; }
        layerK64<4>(accE, Eb, ws + OFF_W61 + 2 * 512, l);
        scatter_f32(eP, accE, q, n);

#pragma unroll 1
        for (int bp = 0; bp < 4; ++bp) {
#pragma unroll
          for (int h = 0; h < 2; ++h) {
            const float* apc = aP + (h * 64 + l) * 8;
            const int re = (n & 8) + bp * 2 + (n & 1);
            const float* epc = eP + (h * 64 + re + (l & 48)) * 8;
            const float4 a0 = *(const float4*)apc;
            const float4 a1 = *(const float4*)(apc + 4);
            const float4 e0 = *(const float4*)epc;
            const float4 e1 = *(const float4*)(epc + 4);
            const float4 b0 = *(const float4*)(sConst + CB61 + 32 * h + 8 * q);
            const float4 b1 = *(const float4*)(sConst + CB61 + 32 * h + 8 * q + 4);
            uint4 ph;
            ph.x = pk2(fmaxf(a0.x + e0.x + b0.x, 0.f), fmaxf(a0.y + e0.y + b0.y, 0.f));
            ph.y = pk2(fmaxf(a0.z + e0.z + b0.z, 0.f), fmaxf(a0.w + e0.w + b0.w, 0.f));
            ph.z = pk2(fmaxf(a1.x + e1.x + b1.x, 0.f), fmaxf(a1.y + e1.y + b1.y, 0.f));
            ph.w = pk2(fmaxf(a1.z + e1.z + b1.z, 0.f), fmaxf(a1.w + e1.w + b1.w, 0.f));
            *(uint4*)(T1 + h * 512 + l * 8) = ph;
          }
          floatx4 acc2[4]; init_accL(acc2, sConst + CB62, n);
          layerK64<2>(acc2, T1, ws + OFF_W62, l);
          scatter_relu_bf16(T2, acc2, q, n);
          floatx4 acc3[4]; init_accL(acc3, sConst + CB63, n);
          layerK64<2>(acc3, T2, ws + OFF_W63, l);
          // rows 4q+2h(+1) belong to batch b = (2q + h) & 3; exclude b == bp
#pragma unroll
          for (int t = 0; t < 4; ++t) {
#pragma unroll
            for (int h = 0; h < 2; ++h) {
              const u32 cand = pk2(fmaxf(acc3[t][2 * h], 0.f), fmaxf(acc3[t][2 * h + 1], 0.f));
              const u32 mx = pkmax(m2p[2 * t + h], cand);
              m2p[2 * t + h] = (((2 * q + h) & 3) != bp) ? mx : m2p[2 * t + h];
            }
          }
        }
      }

      // ---- agg (packed, exact: max/round commute) + mlp7 ----
      {
        u32 agp[8];
#pragma unroll
        for (int i = 0; i < 8; ++i) agp[i] = pkmax(ror16(m1p[i]), m2p[i]);  // m1[r^1]
        scatter_pk(T1, agp, q, n);
        floatx4 acc[4]; init_accL(acc, sConst + CB71, n);
        layerK128(acc, T1, Eb, ws + OFF_W71, l);
        scatter_relu_bf16(T2, acc, q, n);
        floatx4 acc2[4]; init_accL(acc2, sConst + CB72, n);
        layerK64<2>(acc2, T2, ws + OFF_W72, l);
        scatter_relu_bf16(T1, acc2, q, n);
        floatx4 acc3[4]; init_accL(acc3, sConst + CB73, n);
        layerK64<2>(acc3, T1, ws + OFF_W73, l);

        if (it == 0) {
          scatter_relu_bf16(Eb, acc3, q, n);
        } else {
          // ---- post linear + per-(g,b) L2 row normalization ----
          float prr[4] = {0.f, 0.f, 0.f, 0.f}, pii[4] = {0.f, 0.f, 0.f, 0.f};
#pragma unroll
          for (int t = 0; t < 4; ++t) {
            const float wr = sConst[CWPO + (16 * t + n) * 2];
            const float wi = sConst[CWPO + (16 * t + n) * 2 + 1];
#pragma unroll
            for (int r = 0; r < 4; ++r) {
              const float e = fmaxf(acc3[t][r], 0.f);
              prr[r] = fmaf(e, wr, prr[r]);
              pii[r] = fmaf(e, wi, pii[r]);
            }
          }
          const float bpR = sConst[CBPO], bpI = sConst[CBPO + 1];
#pragma unroll
          for (int r = 0; r < 4; ++r) {
#pragma unroll
            for (int off = 1; off < 16; off <<= 1) {
              prr[r] += __shfl_xor(prr[r], off, 16);
              pii[r] += __shfl_xor(pii[r], off, 16);
            }
            prr[r] += bpR;
            pii[r] += bpI;
          }
          const int r = n >> 1, c = n & 1, rp = r ^ 1;
          const float pr_r  = sel4(r,  prr[0], prr[1], prr[2], prr[3]);
          const float pi_r  = sel4(r,  pii[0], pii[1], pii[2], pii[3]);
          const float pr_rp = sel4(rp, prr[0], prr[1], prr[2], prr[3]);
          const float pi_rp = sel4(rp, pii[0], pii[1], pii[2], pii[3]);
          const float num = c ? pi_r : pr_r;
          const float n2  = pr_r * pr_r + pi_r * pi_r + pr_rp * pr_rp + pi_rp * pi_rp;
          if (n < 8) p.out[g0 * 16 + (4 * q + r) * 2 + c] = num / sqrtf(n2);
        }
      }
    }
  }
}

extern "C" void kernel_launch(void* const* d_in, const int* in_sizes, int n_in,
                              void* d_out, int out_size, void* d_ws, size_t ws_size,
                              hipStream_t stream) {
  Params p;
  p.ap    = (const float*)d_in[0];
  p.ef    = (const float*)d_in[1];
  p.wpa   = (const float*)d_in[2];  p.bpa   = (const float*)d_in[3];
  p.wpe   = (const float*)d_in[4];  p.bpe   = (const float*)d_in[5];
  p.w51   = (const float*)d_in[6];  p.b51   = (const float*)d_in[7];
  p.w52   = (const float*)d_in[8];  p.b52   = (const float*)d_in[9];
  p.w53   = (const float*)d_in[10]; p.b53   = (const float*)d_in[11];
  p.w61   = (const float*)d_in[12]; p.b61   = (const float*)d_in[13];
  p.w62   = (const float*)d_in[14]; p.b62   = (const float*)d_in[15];
  p.w63   = (const float*)d_in[16]; p.b63   = (const float*)d_in[17];
  p.w71   = (const float*)d_in[18]; p.b71   = (const float*)d_in[19];
  p.w72   = (const float*)d_in[20]; p.b72   = (const float*)d_in[21];
  p.w73   = (const float*)d_in[22]; p.b73   = (const float*)d_in[23];
  p.wpost = (const float*)d_in[24]; p.bpost = (const float*)d_in[25];
  p.out   = (float*)d_out;
  p.ws    = (u16*)d_ws;
  p.gtot  = in_sizes[0] / 4;  // G from ap_feat [G,B,1]

  hipLaunchKernelGGL(swizzle_weights, dim3(96), dim3(64), 0, stream, p);
  hipLaunchKernelGGL(hetgnn_mfma, dim3(NBLK), dim3(256), 0, stream, p);
}

// Round 6
// 236.417 us; speedup vs baseline: 6.5819x; 1.2198x over previous
//
#include <hip/hip_runtime.h>

// HetGNN fused kernel, round 6: weights global->LDS to kill hoist-driven spill.
// Round-5 evidence: VGPR pinned at 128 regardless of waves_per_eu; WRITE 63.5MB
// unmoved by shrinking m1/m2 => spill source is the compiler hoisting the
// compile-time-addressed global B-frag loads (32 frags = 128 VGPRs in flight
// for one K128 layer), spilling long-lived state as victims. Fix the source:
//  1. All 9 swizzled weight mats staged once per block into LDS (96 KB);
//     B-frags become ds_read_b128 (short latency, no hoist motive, no TCC).
//  2. amdgpu_waves_per_eu(1): 512-reg budget at the 1-block/CU occupancy
//     LDS now forces.
//  3. To fit 160 KB: aP deduplicated (depends only on (g,b): 8 rows, 2 KB)
//     and hoisted out of the iteration loop (a is iteration-invariant) --
//     both exact transforms. LDS total = 96 + 32 + 24 + 4.25 KB = 160000 B.
//  4. Grid 256 blocks x PPW 8: weights staged once per CU.

typedef unsigned short u16;
typedef unsigned int   u32;
typedef __attribute__((ext_vector_type(8))) short short8_t;
typedef __attribute__((ext_vector_type(2))) short short2v;
typedef __attribute__((ext_vector_type(4))) float floatx4;

// u16 offsets of each matrix's fragment block inside d_ws / sW.
#define OFF_W51 0
#define OFF_W61 8192
#define OFF_W71 16384
#define OFF_W52 24576
#define OFF_W53 28672
#define OFF_W62 32768
#define OFF_W63 36864
#define OFF_W72 40960
#define OFF_W73 45056
#define WS_U16  49152

// f32 offsets inside the sConst LDS table.
#define CB51 0
#define CB52 64
#define CB53 128
#define CB61 192
#define CB62 256
#define CB63 320
#define CB71 384
#define CB72 448
#define CB73 512
#define CWPO 576
#define CBPO 704
#define CWPA 768
#define CBPA 832
#define CWPE 896
#define CBPE 1024
#define CSZ  1088

struct Params {
  const float *ap, *ef;
  const float *wpa, *bpa, *wpe, *bpe;
  const float *w51, *b51, *w52, *b52, *w53, *b53;
  const float *w61, *b61, *w62, *b62, *w63, *b63;
  const float *w71, *b71, *w72, *b72, *w73, *b73;
  const float *wpost, *bpost;
  float *out;
  u16 *ws;
  int gtot;
};

__device__ __forceinline__ u16 f2bf(float f) {
  u32 x = __float_as_uint(f);
  return (u16)((x + 0x7fff + ((x >> 16) & 1)) >> 16);  // RNE
}
__device__ __forceinline__ u32 pk2(float a, float b) {
  return (u32)f2bf(a) | ((u32)f2bf(b) << 16);
}
__device__ __forceinline__ u32 pkmax(u32 a, u32 b) {
  const short2v r = __builtin_elementwise_max(__builtin_bit_cast(short2v, a),
                                              __builtin_bit_cast(short2v, b));
  return __builtin_bit_cast(u32, r);
}
__device__ __forceinline__ u32 ror16(u32 x) { return (x >> 16) | (x << 16); }
__device__ __forceinline__ float sel4(int i, float x0, float x1, float x2, float x3) {
  const float lo = (i & 1) ? x1 : x0;
  const float hi = (i & 1) ? x3 : x2;
  return (i & 2) ? hi : lo;
}

// ---------------- setup: swizzle all 9 weight mats into B-frag order ----------------
__global__ void swizzle_weights(Params p) {
  const float* mats[9] = {p.w51, p.w61, p.w71, p.w52, p.w53, p.w62, p.w63, p.w72, p.w73};
  const int fi = blockIdx.x;   // 0..95
  const int l  = threadIdx.x;  // 0..63
  const float* W;
  int t, h;
  if (fi < 48) { W = mats[fi >> 4]; const int loc = fi & 15; t = loc >> 2; h = loc & 3; }
  else { const int j = fi - 48; W = mats[3 + (j >> 3)]; const int loc = j & 7; t = loc >> 1; h = loc & 1; }
  const int n  = 16 * t + (l & 15);
  const int k0 = 32 * h + (l >> 4) * 8;
  u16* dst = p.ws + fi * 512 + l * 8;
#pragma unroll
  for (int j = 0; j < 8; ++j) dst[j] = f2bf(W[(k0 + j) * 64 + n]);
}

// ---------------- main kernel helpers ----------------
__device__ __forceinline__ floatx4 mfma16(short8_t a, short8_t b, floatx4 c) {
  return __builtin_amdgcn_mfma_f32_16x16x32_bf16(a, b, c, 0, 0, 0);
}

template<int TSTRIDE>
__device__ __forceinline__ void layerK64(floatx4* acc, const u16* A, const u16* B, int l) {
  const short8_t a0 = *(const short8_t*)(A + l * 8);
  const short8_t a1 = *(const short8_t*)(A + 512 + l * 8);
#pragma unroll
  for (int t = 0; t < 4; ++t) {
    const short8_t b0 = *(const short8_t*)(B + (t * TSTRIDE + 0) * 512 + l * 8);
    const short8_t b1 = *(const short8_t*)(B + (t * TSTRIDE + 1) * 512 + l * 8);
    acc[t] = mfma16(a0, b0, acc[t]);
    acc[t] = mfma16(a1, b1, acc[t]);
  }
}

__device__ __forceinline__ void layerK128(floatx4* acc, const u16* A0, const u16* A1,
                                          const u16* B, int l) {
  short8_t a[4];
  a[0] = *(const short8_t*)(A0 + l * 8);
  a[1] = *(const short8_t*)(A0 + 512 + l * 8);
  a[2] = *(const short8_t*)(A1 + l * 8);
  a[3] = *(const short8_t*)(A1 + 512 + l * 8);
#pragma unroll
  for (int t = 0; t < 4; ++t)
#pragma unroll
    for (int h = 0; h < 4; ++h)
      acc[t] = mfma16(a[h], *(const short8_t*)(B + (t * 4 + h) * 512 + l * 8), acc[t]);
}

__device__ __forceinline__ void scatter_relu_bf16(u16* dst, const floatx4* acc, int q, int n) {
#pragma unroll
  for (int t = 0; t < 4; ++t) {
    const int kk = (t & 1) * 2 + (n >> 3);
    u16* base = dst + (t >> 1) * 512 + (n & 7);
#pragma unroll
    for (int r = 0; r < 4; ++r)
      base[(4 * q + r + 16 * kk) * 8] = f2bf(fmaxf(acc[t][r], 0.f));
  }
}

__device__ __forceinline__ void scatter_pk(u16* dst, const u32* src, int q, int n) {
#pragma unroll
  for (int t = 0; t < 4; ++t) {
    const int kk = (t & 1) * 2 + (n >> 3);
    u16* base = dst + (t >> 1) * 512 + (n & 7);
#pragma unroll
    for (int half = 0; half < 2; ++half) {
      const u32 v = src[2 * t + half];
      base[(4 * q + 2 * half + 0 + 16 * kk) * 8] = (u16)v;
      base[(4 * q + 2 * half + 1 + 16 * kk) * 8] = (u16)(v >> 16);
    }
  }
}

// eP scatter (full 16 rows, f32), layout word (m + 16kk)*8 + (n&7), frag stride 512.
__device__ __forceinline__ void scatter_f32(float* dst, const floatx4* acc, int q, int n) {
#pragma unroll
  for (int t = 0; t < 4; ++t) {
    const int kk = (t & 1) * 2 + (n >> 3);
    float* base = dst + (t >> 1) * 512 + (n & 7);
#pragma unroll
    for (int r = 0; r < 4; ++r)
      base[(4 * q + r + 16 * kk) * 8] = acc[t][r];
  }
}

// aP dedup scatter: rows 4q+r duplicate in pairs; keep r=0,2 -> d = 2q + (r>>1).
// Layout word (d + 8kk)*8 + (n&7), frag stride 256 f32.
__device__ __forceinline__ void scatter_aP(float* dst, const floatx4* acc, int q, int n) {
#pragma unroll
  for (int t = 0; t < 4; ++t) {
    const int kk = (t & 1) * 2 + (n >> 3);
    float* base = dst + (t >> 1) * 256 + (n & 7);
    base[(2 * q + 0 + 8 * kk) * 8] = acc[t][0];
    base[(2 * q + 1 + 8 * kk) * 8] = acc[t][2];
  }
}

__device__ __forceinline__ void init_accL(floatx4* acc, const float* cb, int n) {
#pragma unroll
  for (int t = 0; t < 4; ++t) {
    const float b = cb[16 * t + n];
    floatx4 v; v[0] = b; v[1] = b; v[2] = b; v[3] = b;
    acc[t] = v;
  }
}

#define NBLK 256
#define PPW  8   // 256 blk * 4 waves * 8 pairs = 8192 pairs = 16384 graphs

__global__ __launch_bounds__(256)
__attribute__((amdgpu_waves_per_eu(1)))
void hetgnn_mfma(Params p) {
  __shared__ __align__(16) u16   sW[WS_U16];    // 96 KB weights (B-frag order)
  __shared__ __align__(16) u16   sB[4][4096];   // 32 KB: Ab,Eb,T1,T2 per wave
  __shared__ __align__(16) float sF[4][1536];   // 24 KB: aP(512) + eP(1024) per wave
  __shared__ __align__(16) float sConst[CSZ];   // 4.25 KB

  const int tid  = threadIdx.x;
  const int wave = tid >> 6;
  const int l    = tid & 63;
  const int q    = l >> 4;
  const int n    = l & 15;

  // ---- stage weights (96 KB) + constants into LDS ----
  {
    const uint4* s = reinterpret_cast<const uint4*>(p.ws);
    uint4* d = reinterpret_cast<uint4*>(sW);
#pragma unroll
    for (int i = 0; i < 24; ++i) d[tid + i * 256] = s[tid + i * 256];
  }
  if (tid < 64) {
    sConst[CB51 + tid] = p.b51[tid];
    sConst[CB52 + tid] = p.b52[tid];
    sConst[CB53 + tid] = p.b53[tid];
    sConst[CB61 + tid] = p.b61[tid];
    sConst[CB62 + tid] = p.b62[tid];
    sConst[CB63 + tid] = p.b63[tid];
    sConst[CB71 + tid] = p.b71[tid];
    sConst[CB72 + tid] = p.b72[tid];
    sConst[CB73 + tid] = p.b73[tid];
    sConst[CWPA + tid] = p.wpa[tid];
    sConst[CBPA + tid] = p.bpa[tid];
    sConst[CBPE + tid] = p.bpe[tid];
  }
  if (tid < 128) {
    sConst[CWPO + tid] = p.wpost[tid];
    sConst[CWPE + tid] = p.wpe[tid];
  }
  if (tid < 2) sConst[CBPO + tid] = p.bpost[tid];
  __syncthreads();

  u16* Ab = sB[wave];
  u16* Eb = Ab + 1024;
  u16* T1 = Ab + 2048;
  u16* T2 = Ab + 3072;
  float* aP = sF[wave];          // 512 f32 (dedup: 8 rows x 64 k)
  float* eP = aP + 512;          // 1024 f32

  const int wslot = blockIdx.x * 4 + wave;

  for (int pi = 0; pi < PPW; ++pi) {
    const int g0 = (wslot * PPW + pi) * 2;   // 2 graphs: g0, g0+1
    if (g0 + 2 > p.gtot) break;

    // ---------------- pre-layer: fill Ab + Eb, A-frag-swizzled ----------------
    {
      const float apv = p.ap[(g0 + (n >> 3)) * 4 + ((n >> 1) & 3)];
      const float f0  = p.ef[(g0 + (n >> 3)) * 16 + (n & 7) * 2];
      const float f1  = p.ef[(g0 + (n >> 3)) * 16 + (n & 7) * 2 + 1];
#pragma unroll
      for (int h = 0; h < 2; ++h) {
        const int fb = 32 * h + 8 * q;
        const float4 wa0 = *(const float4*)(sConst + CWPA + fb);
        const float4 wa1 = *(const float4*)(sConst + CWPA + fb + 4);
        const float4 ba0 = *(const float4*)(sConst + CBPA + fb);
        const float4 ba1 = *(const float4*)(sConst + CBPA + fb + 4);
        uint4 pa;
        pa.x = pk2(fmaxf(fmaf(apv, wa0.x, ba0.x), 0.f), fmaxf(fmaf(apv, wa0.y, ba0.y), 0.f));
        pa.y = pk2(fmaxf(fmaf(apv, wa0.z, ba0.z), 0.f), fmaxf(fmaf(apv, wa0.w, ba0.w), 0.f));
        pa.z = pk2(fmaxf(fmaf(apv, wa1.x, ba1.x), 0.f), fmaxf(fmaf(apv, wa1.y, ba1.y), 0.f));
        pa.w = pk2(fmaxf(fmaf(apv, wa1.z, ba1.z), 0.f), fmaxf(fmaf(apv, wa1.w, ba1.w), 0.f));
        *(uint4*)(Ab + h * 512 + l * 8) = pa;

        const float4 w00 = *(const float4*)(sConst + CWPE + fb);
        const float4 w01 = *(const float4*)(sConst + CWPE + fb + 4);
        const float4 w10 = *(const float4*)(sConst + CWPE + 64 + fb);
        const float4 w11 = *(const float4*)(sConst + CWPE + 64 + fb + 4);
        const float4 be0 = *(const float4*)(sConst + CBPE + fb);
        const float4 be1 = *(const float4*)(sConst + CBPE + fb + 4);
        uint4 pe;
        pe.x = pk2(fmaxf(fmaf(f0, w00.x, fmaf(f1, w10.x, be0.x)), 0.f),
                   fmaxf(fmaf(f0, w00.y, fmaf(f1, w10.y, be0.y)), 0.f));
        pe.y = pk2(fmaxf(fmaf(f0, w00.z, fmaf(f1, w10.z, be0.z)), 0.f),
                   fmaxf(fmaf(f0, w00.w, fmaf(f1, w10.w, be0.w)), 0.f));
        pe.z = pk2(fmaxf(fmaf(f0, w01.x, fmaf(f1, w11.x, be1.x)), 0.f),
                   fmaxf(fmaf(f0, w01.y, fmaf(f1, w11.y, be1.y)), 0.f));
        pe.w = pk2(fmaxf(fmaf(f0, w01.z, fmaf(f1, w11.z, be1.z)), 0.f),
                   fmaxf(fmaf(f0, w01.w, fmaf(f1, w11.w, be1.w)), 0.f));
        *(uint4*)(Eb + h * 512 + l * 8) = pe;
      }
    }

    // ---- aP = a @ w61[:64]: iteration-invariant (a never updates) ----
    {
      floatx4 accA[4];
#pragma unroll
      for (int t = 0; t < 4; ++t) { accA[t][0] = 0.f; accA[t][1] = 0.f; accA[t][2] = 0.f; accA[t][3] = 0.f; }
      layerK64<4>(accA, Ab, sW + OFF_W61, l);
      scatter_aP(aP, accA, q, n);
    }

    // ---------------- 2 shared-weight update iterations ----------------
#pragma unroll 1
    for (int it = 0; it < 2; ++it) {
      // ---- mlp5 -> m1 (packed bf16 pairs) ----
      u32 m1p[8];
      {
        floatx4 acc[4]; init_accL(acc, sConst + CB51, n);
        layerK128(acc, Ab, Eb, sW + OFF_W51, l);
        scatter_relu_bf16(T1, acc, q, n);
        floatx4 acc2[4]; init_accL(acc2, sConst + CB52, n);
        layerK64<2>(acc2, T1, sW + OFF_W52, l);
        scatter_relu_bf16(T2, acc2, q, n);
        floatx4 acc3[4]; init_accL(acc3, sConst + CB53, n);
        layerK64<2>(acc3, T2, sW + OFF_W53, l);
#pragma unroll
        for (int t = 0; t < 4; ++t) {
          m1p[2 * t + 0] = pk2(fmaxf(acc3[t][0], 0.f), fmaxf(acc3[t][1], 0.f));
          m1p[2 * t + 1] = pk2(fmaxf(acc3[t][2], 0.f), fmaxf(acc3[t][3], 0.f));
        }
      }

      // ---- mlp6 -> m2 (masked running max, packed bf16) ----
      u32 m2p[8];
#pragma unroll
      for (int i = 0; i < 8; ++i) m2p[i] = 0u;
      {
        floatx4 accE[4];
#pragma unroll
        for (int t = 0; t < 4; ++t) { accE[t][0] = 0.f; accE[t][1] = 0.f; accE[t][2] = 0.f; accE[t][3] = 0.f; }
        layerK64<4>(accE, Eb, sW + OFF_W61 + 2 * 512, l);
        scatter_f32(eP, accE, q, n);

#pragma unroll 1
        for (int bp = 0; bp < 4; ++bp) {
#pragma unroll
          for (int h = 0; h < 2; ++h) {
            // dedup aP read: row d=(n>>1), kblock q -> broadcast to lane pairs
            const float* apc = aP + h * 256 + ((n >> 1) + 8 * q) * 8;
            const int re = (n & 8) + bp * 2 + (n & 1);
            const float* epc = eP + (h * 64 + re + (l & 48)) * 8;
            const float4 a0 = *(const float4*)apc;
            const float4 a1 = *(const float4*)(apc + 4);
            const float4 e0 = *(const float4*)epc;
            const float4 e1 = *(const float4*)(epc + 4);
            const float4 b0 = *(const float4*)(sConst + CB61 + 32 * h + 8 * q);
            const float4 b1 = *(const float4*)(sConst + CB61 + 32 * h + 8 * q + 4);
            uint4 ph;
            ph.x = pk2(fmaxf(a0.x + e0.x + b0.x, 0.f), fmaxf(a0.y + e0.y + b0.y, 0.f));
            ph.y = pk2(fmaxf(a0.z + e0.z + b0.z, 0.f), fmaxf(a0.w + e0.w + b0.w, 0.f));
            ph.z = pk2(fmaxf(a1.x + e1.x + b1.x, 0.f), fmaxf(a1.y + e1.y + b1.y, 0.f));
            ph.w = pk2(fmaxf(a1.z + e1.z + b1.z, 0.f), fmaxf(a1.w + e1.w + b1.w, 0.f));
            *(uint4*)(T1 + h * 512 + l * 8) = ph;
          }
          floatx4 acc2[4]; init_accL(acc2, sConst + CB62, n);
          layerK64<2>(acc2, T1, sW + OFF_W62, l);
          scatter_relu_bf16(T2, acc2, q, n);
          floatx4 acc3[4]; init_accL(acc3, sConst + CB63, n);
          layerK64<2>(acc3, T2, sW + OFF_W63, l);
#pragma unroll
          for (int t = 0; t < 4; ++t) {
#pragma unroll
            for (int h = 0; h < 2; ++h) {
              const u32 cand = pk2(fmaxf(acc3[t][2 * h], 0.f), fmaxf(acc3[t][2 * h + 1], 0.f));
              const u32 mx = pkmax(m2p[2 * t + h], cand);
              m2p[2 * t + h] = (((2 * q + h) & 3) != bp) ? mx : m2p[2 * t + h];
            }
          }
        }
      }

      // ---- agg (packed, exact) + mlp7 ----
      {
        u32 agp[8];
#pragma unroll
        for (int i = 0; i < 8; ++i) agp[i] = pkmax(ror16(m1p[i]), m2p[i]);
        scatter_pk(T1, agp, q, n);
        floatx4 acc[4]; init_accL(acc, sConst + CB71, n);
        layerK128(acc, T1, Eb, sW + OFF_W71, l);
        scatter_relu_bf16(T2, acc, q, n);
        floatx4 acc2[4]; init_accL(acc2, sConst + CB72, n);
        layerK64<2>(acc2, T2, sW + OFF_W72, l);
        scatter_relu_bf16(T1, acc2, q, n);
        floatx4 acc3[4]; init_accL(acc3, sConst + CB73, n);
        layerK64<2>(acc3, T1, sW + OFF_W73, l);

        if (it == 0) {
          scatter_relu_bf16(Eb, acc3, q, n);
        } else {
          // ---- post linear + per-(g,b) L2 row normalization ----
          float prr[4] = {0.f, 0.f, 0.f, 0.f}, pii[4] = {0.f, 0.f, 0.f, 0.f};
#pragma unroll
          for (int t = 0; t < 4; ++t) {
            const float wr = sConst[CWPO + (16 * t + n) * 2];
            const float wi = sConst[CWPO + (16 * t + n) * 2 + 1];
#pragma unroll
            for (int r = 0; r < 4; ++r) {
              const float e = fmaxf(acc3[t][r], 0.f);
              prr[r] = fmaf(e, wr, prr[r]);
              pii[r] = fmaf(e, wi, pii[r]);
            }
          }
          const float bpR = sConst[CBPO], bpI = sConst[CBPO + 1];
#pragma unroll
          for (int r = 0; r < 4; ++r) {
#pragma unroll
            for (int off = 1; off < 16; off <<= 1) {
              prr[r] += __shfl_xor(prr[r], off, 16);
              pii[r] += __shfl_xor(pii[r], off, 16);
            }
            prr[r] += bpR;
            pii[r] += bpI;
          }
          const int r = n >> 1, c = n & 1, rp = r ^ 1;
          const float pr_r  = sel4(r,  prr[0], prr[1], prr[2], prr[3]);
          const float pi_r  = sel4(r,  pii[0], pii[1], pii[2], pii[3]);
          const float pr_rp = sel4(rp, prr[0], prr[1], prr[2], prr[3]);
          const float pi_rp = sel4(rp, pii[0], pii[1], pii[2], pii[3]);
          const float num = c ? pi_r : pr_r;
          const float n2  = pr_r * pr_r + pi_r * pi_r + pr_rp * pr_rp + pi_rp * pi_rp;
          if (n < 8) p.out[g0 * 16 + (4 * q + r) * 2 + c] = num / sqrtf(n2);
        }
      }
    }
  }
}

extern "C" void kernel_launch(void* const* d_in, const int* in_sizes, int n_in,
                              void* d_out, int out_size, void* d_ws, size_t ws_size,
                              hipStream_t stream) {
  Params p;
  p.ap    = (const float*)d_in[0];
  p.ef    = (const float*)d_in[1];
  p.wpa   = (const float*)d_in[2];  p.bpa   = (const float*)d_in[3];
  p.wpe   = (const float*)d_in[4];  p.bpe   = (const float*)d_in[5];
  p.w51   = (const float*)d_in[6];  p.b51   = (const float*)d_in[7];
  p.w52   = (const float*)d_in[8];  p.b52   = (const float*)d_in[9];
  p.w53   = (const float*)d_in[10]; p.b53   = (const float*)d_in[11];
  p.w61   = (const float*)d_in[12]; p.b61   = (const float*)d_in[13];
  p.w62   = (const float*)d_in[14]; p.b62   = (const float*)d_in[15];
  p.w63   = (const float*)d_in[16]; p.b63   = (const float*)d_in[17];
  p.w71   = (const float*)d_in[18]; p.b71   = (const float*)d_in[19];
  p.w72   = (const float*)d_in[20]; p.b72   = (const float*)d_in[21];
  p.w73   = (const float*)d_in[22]; p.b73   = (const float*)d_in[23];
  p.wpost = (const float*)d_in[24]; p.bpost = (const float*)d_in[25];
  p.out   = (float*)d_out;
  p.ws    = (u16*)d_ws;
  p.gtot  = in_sizes[0] / 4;  // G from ap_feat [G,B,1]

  hipLaunchKernelGGL(swizzle_weights, dim3(96), dim3(64), 0, stream, p);
  hipLaunchKernelGGL(hetgnn_mfma, dim3(NBLK), dim3(256), 0, stream, p);
}

// Round 7
// 194.499 us; speedup vs baseline: 8.0004x; 1.2155x over previous
//
#include <hip/hip_runtime.h>

// HetGNN fused kernel, round 7: single dispatch + 2 waves/SIMD.
// R6 confirmed spills gone; bottleneck = latency at 1 wave/SIMD (19K cy/stage-chain
// vs ~3K compute) + a ~105us bench-vs-kernel overhead tied to the 2-dispatch
// structure. Changes:
//  1. Weight swizzle merged into main-kernel staging (f32 global -> bf16 B-frag
//     LDS directly); swizzle_weights kernel and d_ws eliminated -> 1 dispatch.
//  2. 512-thread blocks: 8 waves/block = 2 waves/SIMD (balanced), PPW=4
//     (256*8*4 = 8192 pairs exactly).
//  3. LDS diet to fit 96KB weights + 8 wave-buffers + consts = 160000 B:
//     - T2 eliminated (T1 reused: A-frag regs load before scatter, DS in-order)
//     - Ab eliminated (a-rows staged into T1; recomputed at it=1 start, exact)
//     - aP/eP stored bf16 (A-swizzled); only numerics change this round.

typedef unsigned short u16;
typedef unsigned int   u32;
typedef __attribute__((ext_vector_type(8))) short short8_t;
typedef __attribute__((ext_vector_type(2))) short short2v;
typedef __attribute__((ext_vector_type(4))) float floatx4;

// u16 offsets of each matrix's fragment block inside sW (fi*512 ordering).
#define OFF_W51 0
#define OFF_W61 8192
#define OFF_W71 16384
#define OFF_W52 24576
#define OFF_W53 28672
#define OFF_W62 32768
#define OFF_W63 36864
#define OFF_W72 40960
#define OFF_W73 45056
#define WS_U16  49152

// f32 offsets inside the sConst LDS table.
#define CB51 0
#define CB52 64
#define CB53 128
#define CB61 192
#define CB62 256
#define CB63 320
#define CB71 384
#define CB72 448
#define CB73 512
#define CWPO 576
#define CBPO 704
#define CWPA 768
#define CBPA 832
#define CWPE 896
#define CBPE 1024
#define CSZ  1088

#define PW_U16 3584   // per-wave activation LDS: Eb 1024 | T1 1024 | eP 1024 | aP 512

struct Params {
  const float *ap, *ef;
  const float *wpa, *bpa, *wpe, *bpe;
  const float *w51, *b51, *w52, *b52, *w53, *b53;
  const float *w61, *b61, *w62, *b62, *w63, *b63;
  const float *w71, *b71, *w72, *b72, *w73, *b73;
  const float *wpost, *bpost;
  float *out;
  int gtot;
};

__device__ __forceinline__ u16 f2bf(float f) {
  u32 x = __float_as_uint(f);
  return (u16)((x + 0x7fff + ((x >> 16) & 1)) >> 16);  // RNE
}
__device__ __forceinline__ u32 pk2(float a, float b) {
  return (u32)f2bf(a) | ((u32)f2bf(b) << 16);
}
__device__ __forceinline__ float blo(u32 v) { return __uint_as_float(v << 16); }
__device__ __forceinline__ float bhi(u32 v) { return __uint_as_float(v & 0xffff0000u); }
__device__ __forceinline__ u32 pkmax(u32 a, u32 b) {
  const short2v r = __builtin_elementwise_max(__builtin_bit_cast(short2v, a),
                                              __builtin_bit_cast(short2v, b));
  return __builtin_bit_cast(u32, r);
}
__device__ __forceinline__ u32 ror16(u32 x) { return (x >> 16) | (x << 16); }
__device__ __forceinline__ float sel4(int i, float x0, float x1, float x2, float x3) {
  const float lo = (i & 1) ? x1 : x0;
  const float hi = (i & 1) ? x3 : x2;
  return (i & 2) ? hi : lo;
}

__device__ __forceinline__ floatx4 mfma16(short8_t a, short8_t b, floatx4 c) {
  return __builtin_amdgcn_mfma_f32_16x16x32_bf16(a, b, c, 0, 0, 0);
}

template<int TSTRIDE>
__device__ __forceinline__ void layerK64(floatx4* acc, const u16* A, const u16* B, int l) {
  const short8_t a0 = *(const short8_t*)(A + l * 8);
  const short8_t a1 = *(const short8_t*)(A + 512 + l * 8);
#pragma unroll
  for (int t = 0; t < 4; ++t) {
    const short8_t b0 = *(const short8_t*)(B + (t * TSTRIDE + 0) * 512 + l * 8);
    const short8_t b1 = *(const short8_t*)(B + (t * TSTRIDE + 1) * 512 + l * 8);
    acc[t] = mfma16(a0, b0, acc[t]);
    acc[t] = mfma16(a1, b1, acc[t]);
  }
}

__device__ __forceinline__ void layerK128(floatx4* acc, const u16* A0, const u16* A1,
                                          const u16* B, int l) {
  short8_t a[4];
  a[0] = *(const short8_t*)(A0 + l * 8);
  a[1] = *(const short8_t*)(A0 + 512 + l * 8);
  a[2] = *(const short8_t*)(A1 + l * 8);
  a[3] = *(const short8_t*)(A1 + 512 + l * 8);
#pragma unroll
  for (int t = 0; t < 4; ++t)
#pragma unroll
    for (int h = 0; h < 4; ++h)
      acc[t] = mfma16(a[h], *(const short8_t*)(B + (t * 4 + h) * 512 + l * 8), acc[t]);
}

// C-layout regs -> A-frag-swizzled bf16 LDS (with relu). Element (m=4q+r, f=16t+n).
__device__ __forceinline__ void scatter_relu_bf16(u16* dst, const floatx4* acc, int q, int n) {
#pragma unroll
  for (int t = 0; t < 4; ++t) {
    const int kk = (t & 1) * 2 + (n >> 3);
    u16* base = dst + (t >> 1) * 512 + (n & 7);
#pragma unroll
    for (int r = 0; r < 4; ++r)
      base[(4 * q + r + 16 * kk) * 8] = f2bf(fmaxf(acc[t][r], 0.f));
  }
}

// Same but no relu (eP can be negative), bf16 dst.
__device__ __forceinline__ void scatter_bf16(u16* dst, const floatx4* acc, int q, int n) {
#pragma unroll
  for (int t = 0; t < 4; ++t) {
    const int kk = (t & 1) * 2 + (n >> 3);
    u16* base = dst + (t >> 1) * 512 + (n & 7);
#pragma unroll
    for (int r = 0; r < 4; ++r)
      base[(4 * q + r + 16 * kk) * 8] = f2bf(acc[t][r]);
  }
}

// Packed-bf16 variant: src[2t+half] holds rows (4q+2*half, 4q+2*half+1).
__device__ __forceinline__ void scatter_pk(u16* dst, const u32* src, int q, int n) {
#pragma unroll
  for (int t = 0; t < 4; ++t) {
    const int kk = (t & 1) * 2 + (n >> 3);
    u16* base = dst + (t >> 1) * 512 + (n & 7);
#pragma unroll
    for (int half = 0; half < 2; ++half) {
      const u32 v = src[2 * t + half];
      base[(4 * q + 2 * half + 0 + 16 * kk) * 8] = (u16)v;
      base[(4 * q + 2 * half + 1 + 16 * kk) * 8] = (u16)(v >> 16);
    }
  }
}

// aP dedup scatter (bf16): rows duplicate in pairs; keep r=0,2 -> d = 2q+(r>>1).
// Frag stride 256 u16; chunk (d + 8kk)*8 + (n&7).
__device__ __forceinline__ void scatter_aP(u16* dst, const floatx4* acc, int q, int n) {
#pragma unroll
  for (int t = 0; t < 4; ++t) {
    const int kk = (t & 1) * 2 + (n >> 3);
    u16* base = dst + (t >> 1) * 256 + (n & 7);
    base[(2 * q + 0 + 8 * kk) * 8] = f2bf(acc[t][0]);
    base[(2 * q + 1 + 8 * kk) * 8] = f2bf(acc[t][2]);
  }
}

__device__ __forceinline__ void init_accL(floatx4* acc, const float* cb, int n) {
#pragma unroll
  for (int t = 0; t < 4; ++t) {
    const float b = cb[16 * t + n];
    floatx4 v; v[0] = b; v[1] = b; v[2] = b; v[3] = b;
    acc[t] = v;
  }
}

// Stage a-rows (A-frag-swizzled) into dst; exact same math both times it's called.
__device__ __forceinline__ void fill_a(u16* dst, float apv, int q, int l, const float* sc) {
#pragma unroll
  for (int h = 0; h < 2; ++h) {
    const int fb = 32 * h + 8 * q;
    const float4 wa0 = *(const float4*)(sc + CWPA + fb);
    const float4 wa1 = *(const float4*)(sc + CWPA + fb + 4);
    const float4 ba0 = *(const float4*)(sc + CBPA + fb);
    const float4 ba1 = *(const float4*)(sc + CBPA + fb + 4);
    uint4 pa;
    pa.x = pk2(fmaxf(fmaf(apv, wa0.x, ba0.x), 0.f), fmaxf(fmaf(apv, wa0.y, ba0.y), 0.f));
    pa.y = pk2(fmaxf(fmaf(apv, wa0.z, ba0.z), 0.f), fmaxf(fmaf(apv, wa0.w, ba0.w), 0.f));
    pa.z = pk2(fmaxf(fmaf(apv, wa1.x, ba1.x), 0.f), fmaxf(fmaf(apv, wa1.y, ba1.y), 0.f));
    pa.w = pk2(fmaxf(fmaf(apv, wa1.z, ba1.z), 0.f), fmaxf(fmaf(apv, wa1.w, ba1.w), 0.f));
    *(uint4*)(dst + h * 512 + l * 8) = pa;
  }
}

#define NBLK 256
#define PPW  4   // 256 blk * 8 waves * 4 pairs = 8192 pairs = 16384 graphs

__global__ __launch_bounds__(512)
__attribute__((amdgpu_waves_per_eu(2)))
void hetgnn_mfma(Params p) {
  __shared__ __align__(16) u16   sW[WS_U16];       // 96 KB weights (B-frag order)
  __shared__ __align__(16) u16   sAct[8 * PW_U16]; // 56 KB: 8 waves x (Eb|T1|eP|aP)
  __shared__ __align__(16) float sConst[CSZ];      // 4.25 KB
  // total 98304 + 57344 + 4352 = 160000 B <= 163840

  const int tid  = threadIdx.x;
  const int wave = tid >> 6;
  const int l    = tid & 63;
  const int q    = l >> 4;
  const int n    = l & 15;

  // ---- stage + swizzle weights (f32 global -> bf16 B-frag LDS), 12 frags/wave ----
  {
    const float* mats[9] = {p.w51, p.w61, p.w71, p.w52, p.w53, p.w62, p.w63, p.w72, p.w73};
    for (int i = 0; i < 12; ++i) {
      const int fi = wave * 12 + i;   // wave-uniform
      const float* W;
      int t, h;
      if (fi < 48) { W = mats[fi >> 4]; const int loc = fi & 15; t = loc >> 2; h = loc & 3; }
      else { const int j = fi - 48; W = mats[3 + (j >> 3)]; const int loc = j & 7; t = loc >> 1; h = loc & 1; }
      const int nn = 16 * t + (l & 15);
      const int k0 = 32 * h + (l >> 4) * 8;
      float w[8];
#pragma unroll
      for (int j = 0; j < 8; ++j) w[j] = W[(k0 + j) * 64 + nn];
      uint4 o;
      o.x = pk2(w[0], w[1]); o.y = pk2(w[2], w[3]);
      o.z = pk2(w[4], w[5]); o.w = pk2(w[6], w[7]);
      *(uint4*)(sW + fi * 512 + l * 8) = o;
    }
  }
  if (tid < 64) {
    sConst[CB51 + tid] = p.b51[tid];
    sConst[CB52 + tid] = p.b52[tid];
    sConst[CB53 + tid] = p.b53[tid];
    sConst[CB61 + tid] = p.b61[tid];
    sConst[CB62 + tid] = p.b62[tid];
    sConst[CB63 + tid] = p.b63[tid];
    sConst[CB71 + tid] = p.b71[tid];
    sConst[CB72 + tid] = p.b72[tid];
    sConst[CB73 + tid] = p.b73[tid];
    sConst[CWPA + tid] = p.wpa[tid];
    sConst[CBPA + tid] = p.bpa[tid];
    sConst[CBPE + tid] = p.bpe[tid];
  }
  if (tid < 128) {
    sConst[CWPO + tid] = p.wpost[tid];
    sConst[CWPE + tid] = p.wpe[tid];
  }
  if (tid < 2) sConst[CBPO + tid] = p.bpost[tid];
  __syncthreads();

  u16* Eb  = sAct + wave * PW_U16;
  u16* T1  = Eb + 1024;
  u16* eP  = Eb + 2048;   // bf16, A-swizzled, 16 rows
  u16* aPb = Eb + 3072;   // bf16, A-swizzled dedup, 8 rows (512 u16)

  const int wslot = blockIdx.x * 8 + wave;

  for (int pi = 0; pi < PPW; ++pi) {
    const int g0 = (wslot * PPW + pi) * 2;   // 2 graphs: g0, g0+1
    if (g0 + 2 > p.gtot) break;

    // ---------------- pre-layer: a-rows -> T1, e-rows -> Eb (A-swizzled) ----------------
    const float apv = p.ap[(g0 + (n >> 3)) * 4 + ((n >> 1) & 3)];
    {
      const float f0 = p.ef[(g0 + (n >> 3)) * 16 + (n & 7) * 2];
      const float f1 = p.ef[(g0 + (n >> 3)) * 16 + (n & 7) * 2 + 1];
      fill_a(T1, apv, q, l, sConst);
#pragma unroll
      for (int h = 0; h < 2; ++h) {
        const int fb = 32 * h + 8 * q;
        const float4 w00 = *(const float4*)(sConst + CWPE + fb);
        const float4 w01 = *(const float4*)(sConst + CWPE + fb + 4);
        const float4 w10 = *(const float4*)(sConst + CWPE + 64 + fb);
        const float4 w11 = *(const float4*)(sConst + CWPE + 64 + fb + 4);
        const float4 be0 = *(const float4*)(sConst + CBPE + fb);
        const float4 be1 = *(const float4*)(sConst + CBPE + fb + 4);
        uint4 pe;
        pe.x = pk2(fmaxf(fmaf(f0, w00.x, fmaf(f1, w10.x, be0.x)), 0.f),
                   fmaxf(fmaf(f0, w00.y, fmaf(f1, w10.y, be0.y)), 0.f));
        pe.y = pk2(fmaxf(fmaf(f0, w00.z, fmaf(f1, w10.z, be0.z)), 0.f),
                   fmaxf(fmaf(f0, w00.w, fmaf(f1, w10.w, be0.w)), 0.f));
        pe.z = pk2(fmaxf(fmaf(f0, w01.x, fmaf(f1, w11.x, be1.x)), 0.f),
                   fmaxf(fmaf(f0, w01.y, fmaf(f1, w11.y, be1.y)), 0.f));
        pe.w = pk2(fmaxf(fmaf(f0, w01.z, fmaf(f1, w11.z, be1.z)), 0.f),
                   fmaxf(fmaf(f0, w01.w, fmaf(f1, w11.w, be1.w)), 0.f));
        *(uint4*)(Eb + h * 512 + l * 8) = pe;
      }
    }

    // ---- aP = a @ w61[:64]: iteration-invariant (a never updates), from T1-a ----
    {
      floatx4 accA[4];
#pragma unroll
      for (int t = 0; t < 4; ++t) { accA[t][0] = 0.f; accA[t][1] = 0.f; accA[t][2] = 0.f; accA[t][3] = 0.f; }
      layerK64<4>(accA, T1, sW + OFF_W61, l);
      scatter_aP(aPb, accA, q, n);
    }

    // ---------------- 2 shared-weight update iterations ----------------
#pragma unroll 1
    for (int it = 0; it < 2; ++it) {
      if (it == 1) fill_a(T1, apv, q, l, sConst);   // T1-a was consumed in it0

      // ---- mlp5 -> m1 (packed bf16 pairs) ----
      u32 m1p[8];
      {
        floatx4 acc[4]; init_accL(acc, sConst + CB51, n);
        layerK128(acc, T1, Eb, sW + OFF_W51, l);   // A-regs load before scatter: T1 reuse safe
        scatter_relu_bf16(T1, acc, q, n);
        floatx4 acc2[4]; init_accL(acc2, sConst + CB52, n);
        layerK64<2>(acc2, T1, sW + OFF_W52, l);
        scatter_relu_bf16(T1, acc2, q, n);
        floatx4 acc3[4]; init_accL(acc3, sConst + CB53, n);
        layerK64<2>(acc3, T1, sW + OFF_W53, l);
#pragma unroll
        for (int t = 0; t < 4; ++t) {
          m1p[2 * t + 0] = pk2(fmaxf(acc3[t][0], 0.f), fmaxf(acc3[t][1], 0.f));
          m1p[2 * t + 1] = pk2(fmaxf(acc3[t][2], 0.f), fmaxf(acc3[t][3], 0.f));
        }
      }

      // ---- mlp6 -> m2 (masked running max, packed bf16) ----
      u32 m2p[8];
#pragma unroll
      for (int i = 0; i < 8; ++i) m2p[i] = 0u;
      {
        floatx4 accE[4];
#pragma unroll
        for (int t = 0; t < 4; ++t) { accE[t][0] = 0.f; accE[t][1] = 0.f; accE[t][2] = 0.f; accE[t][3] = 0.f; }
        layerK64<4>(accE, Eb, sW + OFF_W61 + 2 * 512, l);
        scatter_bf16(eP, accE, q, n);

#pragma unroll 1
        for (int bp = 0; bp < 4; ++bp) {
          // h-build: h = relu(aP[d] + eP[re] + b61), straight into T1 A-frags
          const int kkl = l >> 4;
          const int d   = (l & 15) >> 1;
          const int re  = (n & 8) + bp * 2 + (n & 1);
#pragma unroll
          for (int h = 0; h < 2; ++h) {
            const uint4 av = *(const uint4*)(aPb + h * 256 + (d + 8 * kkl) * 8);
            const uint4 ev = *(const uint4*)(eP + h * 512 + (re + 16 * kkl) * 8);
            const float4 b0 = *(const float4*)(sConst + CB61 + 32 * h + 8 * kkl);
            const float4 b1 = *(const float4*)(sConst + CB61 + 32 * h + 8 * kkl + 4);
            uint4 ph;
            ph.x = pk2(fmaxf(blo(av.x) + blo(ev.x) + b0.x, 0.f),
                       fmaxf(bhi(av.x) + bhi(ev.x) + b0.y, 0.f));
            ph.y = pk2(fmaxf(blo(av.y) + blo(ev.y) + b0.z, 0.f),
                       fmaxf(bhi(av.y) + bhi(ev.y) + b0.w, 0.f));
            ph.z = pk2(fmaxf(blo(av.z) + blo(ev.z) + b1.x, 0.f),
                       fmaxf(bhi(av.z) + bhi(ev.z) + b1.y, 0.f));
            ph.w = pk2(fmaxf(blo(av.w) + blo(ev.w) + b1.z, 0.f),
                       fmaxf(bhi(av.w) + bhi(ev.w) + b1.w, 0.f));
            *(uint4*)(T1 + h * 512 + l * 8) = ph;
          }
          floatx4 acc2[4]; init_accL(acc2, sConst + CB62, n);
          layerK64<2>(acc2, T1, sW + OFF_W62, l);
          scatter_relu_bf16(T1, acc2, q, n);
          floatx4 acc3[4]; init_accL(acc3, sConst + CB63, n);
          layerK64<2>(acc3, T1, sW + OFF_W63, l);
#pragma unroll
          for (int t = 0; t < 4; ++t) {
#pragma unroll
            for (int h = 0; h < 2; ++h) {
              const u32 cand = pk2(fmaxf(acc3[t][2 * h], 0.f), fmaxf(acc3[t][2 * h + 1], 0.f));
              const u32 mx = pkmax(m2p[2 * t + h], cand);
              m2p[2 * t + h] = (((2 * q + h) & 3) != bp) ? mx : m2p[2 * t + h];
            }
          }
        }
      }

      // ---- agg (packed, exact) + mlp7 ----
      {
        u32 agp[8];
#pragma unroll
        for (int i = 0; i < 8; ++i) agp[i] = pkmax(ror16(m1p[i]), m2p[i]);
        scatter_pk(T1, agp, q, n);
        floatx4 acc[4]; init_accL(acc, sConst + CB71, n);
        layerK128(acc, T1, Eb, sW + OFF_W71, l);
        scatter_relu_bf16(T1, acc, q, n);
        floatx4 acc2[4]; init_accL(acc2, sConst + CB72, n);
        layerK64<2>(acc2, T1, sW + OFF_W72, l);
        scatter_relu_bf16(T1, acc2, q, n);
        floatx4 acc3[4]; init_accL(acc3, sConst + CB73, n);
        layerK64<2>(acc3, T1, sW + OFF_W73, l);

        if (it == 0) {
          scatter_relu_bf16(Eb, acc3, q, n);
        } else {
          // ---- post linear + per-(g,b) L2 row normalization ----
          float prr[4] = {0.f, 0.f, 0.f, 0.f}, pii[4] = {0.f, 0.f, 0.f, 0.f};
#pragma unroll
          for (int t = 0; t < 4; ++t) {
            const float wr = sConst[CWPO + (16 * t + n) * 2];
            const float wi = sConst[CWPO + (16 * t + n) * 2 + 1];
#pragma unroll
            for (int r = 0; r < 4; ++r) {
              const float e = fmaxf(acc3[t][r], 0.f);
              prr[r] = fmaf(e, wr, prr[r]);
              pii[r] = fmaf(e, wi, pii[r]);
            }
          }
          const float bpR = sConst[CBPO], bpI = sConst[CBPO + 1];
#pragma unroll
          for (int r = 0; r < 4; ++r) {
#pragma unroll
            for (int off = 1; off < 16; off <<= 1) {
              prr[r] += __shfl_xor(prr[r], off, 16);
              pii[r] += __shfl_xor(pii[r], off, 16);
            }
            prr[r] += bpR;
            pii[r] += bpI;
          }
          const int r = n >> 1, c = n & 1, rp = r ^ 1;
          const float pr_r  = sel4(r,  prr[0], prr[1], prr[2], prr[3]);
          const float pi_r  = sel4(r,  pii[0], pii[1], pii[2], pii[3]);
          const float pr_rp = sel4(rp, prr[0], prr[1], prr[2], prr[3]);
          const float pi_rp = sel4(rp, pii[0], pii[1], pii[2], pii[3]);
          const float num = c ? pi_r : pr_r;
          const float n2  = pr_r * pr_r + pi_r * pi_r + pr_rp * pr_rp + pi_rp * pi_rp;
          if (n < 8) p.out[g0 * 16 + (4 * q + r) * 2 + c] = num / sqrtf(n2);
        }
      }
    }
  }
}

extern "C" void kernel_launch(void* const* d_in, const int* in_sizes, int n_in,
                              void* d_out, int out_size, void* d_ws, size_t ws_size,
                              hipStream_t stream) {
  Params p;
  p.ap    = (const float*)d_in[0];
  p.ef    = (const float*)d_in[1];
  p.wpa   = (const float*)d_in[2];  p.bpa   = (const float*)d_in[3];
  p.wpe   = (const float*)d_in[4];  p.bpe   = (const float*)d_in[5];
  p.w51   = (const float*)d_in[6];  p.b51   = (const float*)d_in[7];
  p.w52   = (const float*)d_in[8];  p.b52   = (const float*)d_in[9];
  p.w53   = (const float*)d_in[10]; p.b53   = (const float*)d_in[11];
  p.w61   = (const float*)d_in[12]; p.b61   = (const float*)d_in[13];
  p.w62   = (const float*)d_in[14]; p.b62   = (const float*)d_in[15];
  p.w63   = (const float*)d_in[16]; p.b63   = (const float*)d_in[17];
  p.w71   = (const float*)d_in[18]; p.b71   = (const float*)d_in[19];
  p.w72   = (const float*)d_in[20]; p.b72   = (const float*)d_in[21];
  p.w73   = (const float*)d_in[22]; p.b73   = (const float*)d_in[23];
  p.wpost = (const float*)d_in[24]; p.bpost = (const float*)d_in[25];
  p.out   = (float*)d_out;
  p.gtot  = in_sizes[0] / 4;  // G from ap_feat [G,B,1]

  hipLaunchKernelGGL(hetgnn_mfma, dim3(NBLK), dim3(512), 0, stream, p);
}